// Round 1
// baseline (8228.974 us; speedup 1.0000x reference)
//
#include <hip/hip_runtime.h>
#include <math.h>

#define NL   6
#define DM   768
#define NH   8
#define DQ   96
#define DFF  3072
#define BB   8
#define TT   512
#define NTOK (BB*TT)      // 4096 tokens
#define NREL 201
#define WIN  99
#define ODIM 80

// ---------------- input transpose: x(B,T,D) -> src(token n=t*8+b, D) ----------------
__global__ void k_transpose_in(const float* __restrict__ x, float* __restrict__ src) {
  int n = blockIdx.x;               // n = t*8 + b
  int t = n >> 3, b = n & 7;
  const float* xi = x + ((size_t)b*TT + t)*DM;
  float* so = src + (size_t)n*DM;
  for (int d = threadIdx.x; d < DM; d += blockDim.x) so[d] = xi[d];
}

// ---------------- weight transforms (per layer) ----------------
// wq[h][f][a] -> wqt[c=h*96+a][f]   (NT layout for GEMM)
__global__ void k_transform_qkv(const float* __restrict__ wq, const float* __restrict__ wk,
                                const float* __restrict__ wv,
                                float* __restrict__ qt, float* __restrict__ kt2,
                                float* __restrict__ vt) {
  int idx = blockIdx.x*256 + threadIdx.x;     // over DM*DM, f fastest
  if (idx >= DM*DM) return;
  int f = idx % DM, c = idx / DM;
  int h = c / DQ, a = c % DQ;
  size_t si = ((size_t)h*DM + f)*DQ + a;
  qt[idx] = wq[si]; kt2[idx] = wk[si]; vt[idx] = wv[si];
}

// wo[r=h*96+a][d] -> wot[d][r]
__global__ void k_transpose_wo(const float* __restrict__ wo, float* __restrict__ wot) {
  int idx = blockIdx.x*256 + threadIdx.x;
  if (idx >= DM*DM) return;
  int r = idx % DM, d = idx / DM;
  wot[idx] = wo[(size_t)r*DM + d];
}

// emb[h][e][a] -> embt[h][a][e]
__global__ void k_transpose_emb(const float* __restrict__ emb, float* __restrict__ embt) {
  int idx = blockIdx.x*256 + threadIdx.x;     // over NH*DQ*NREL, e fastest
  if (idx >= NH*DQ*NREL) return;
  int e = idx % NREL; int a = (idx / NREL) % DQ; int h = idx / (NREL*DQ);
  embt[idx] = emb[((size_t)h*NREL + e)*DQ + a];
}

// kb(n=t*8+b, c=h*96+a) -> kt(b,h,a,t)
__global__ void k_transpose_k(const float* __restrict__ kb, float* __restrict__ kt) {
  int idx = blockIdx.x*256 + threadIdx.x;     // over BB*NH*DQ*TT, t fastest
  if (idx >= BB*NH*DQ*TT) return;
  int t = idx & (TT-1);
  int r = idx >> 9;                 // (b*8+h)*96 + a
  int a = r % DQ;
  int bh = r / DQ;
  int h = bh & (NH-1), b = bh >> 3;
  kt[idx] = kb[((size_t)t*BB + b)*DM + h*DQ + a];
}

// ---------------- tiled fp32 NT GEMM: C[M,N] = A[M,K] * Bt[N,K]^T ----------------
template<int BM, int BN, int BK, int TM, int TN, bool RELU, bool PERMOUT>
__global__ __launch_bounds__((BM/TM)*(BN/TN))
void k_gemm_nt(const float* __restrict__ A, const float* __restrict__ Bt,
               const float* __restrict__ bias, float* __restrict__ C,
               int M, int N, int K, float scale) {
  constexpr int NTX = BN/TN, NTY = BM/TM, NTH = NTX*NTY;
  __shared__ float As[BK][BM+4];
  __shared__ float Bs[BK][BN+4];
  const int tid = threadIdx.x;
  const int tx = tid % NTX, ty = tid / NTX;
  const int m0 = blockIdx.y*BM, n0 = blockIdx.x*BN;
  float acc[TM][TN];
  #pragma unroll
  for (int i=0;i<TM;++i)
    #pragma unroll
    for (int j=0;j<TN;++j) acc[i][j]=0.f;

  for (int k0 = 0; k0 < K; k0 += BK) {
    #pragma unroll
    for (int l = tid*4; l < BM*BK; l += NTH*4) {
      int mm = l / BK, kk = l % BK;
      float4 av = *(const float4*)(A + (size_t)(m0+mm)*K + k0+kk);
      As[kk+0][mm]=av.x; As[kk+1][mm]=av.y; As[kk+2][mm]=av.z; As[kk+3][mm]=av.w;
    }
    #pragma unroll
    for (int l = tid*4; l < BN*BK; l += NTH*4) {
      int nn = l / BK, kk = l % BK;
      float4 bv = make_float4(0.f,0.f,0.f,0.f);
      if (n0+nn < N) bv = *(const float4*)(Bt + (size_t)(n0+nn)*K + k0+kk);
      Bs[kk+0][nn]=bv.x; Bs[kk+1][nn]=bv.y; Bs[kk+2][nn]=bv.z; Bs[kk+3][nn]=bv.w;
    }
    __syncthreads();
    #pragma unroll
    for (int kk = 0; kk < BK; ++kk) {
      float a[TM], b[TN];
      #pragma unroll
      for (int i=0;i<TM;++i) a[i] = As[kk][ty*TM+i];
      #pragma unroll
      for (int j=0;j<TN;++j) b[j] = Bs[kk][tx*TN+j];
      #pragma unroll
      for (int i=0;i<TM;++i)
        #pragma unroll
        for (int j=0;j<TN;++j) acc[i][j] = fmaf(a[i], b[j], acc[i][j]);
    }
    __syncthreads();
  }
  #pragma unroll
  for (int i=0;i<TM;++i) {
    int m = m0 + ty*TM + i;
    int row = PERMOUT ? ((m & 7)*TT + (m >> 3)) : m;   // token n=t*8+b -> out row b*512+t
    #pragma unroll
    for (int j=0;j<TN;++j) {
      int n = n0 + tx*TN + j;
      if (n < N) {
        float vv = acc[i][j]*scale + (bias ? bias[n] : 0.f);
        if (RELU) vv = fmaxf(vv, 0.f);
        C[(size_t)row*N + n] = vv;
      }
    }
  }
}

// ---------------- banded attention: one wave per (b,h,query) ----------------
// window |j-i|<=99 is exact: out-of-band logits get -1e8 in the reference -> exp underflows to 0.
__global__ __launch_bounds__(64)
void k_attn(const float* __restrict__ q,    // (n, 768)
            const float* __restrict__ kt,   // (b,h,a,t)
            const float* __restrict__ v,    // (n, 768)
            const float* __restrict__ embt, // (h,a,e)
            float* __restrict__ o) {        // (n, 768)
  int gid = blockIdx.x;
  int i = gid & (TT-1);
  int h = (gid >> 9) & (NH-1);
  int b = gid >> 12;
  int lane = threadIdx.x;
  int wlo = max(i-WIN, 0), whi = min(i+WIN, TT-1);
  int nw = whi - wlo + 1;                   // 100..199
  __shared__ float sq[DQ];
  __shared__ float sp[256];
  for (int a = lane; a < DQ; a += 64)
    sq[a] = q[((size_t)i*BB + b)*DM + h*DQ + a];
  __syncthreads();
  const float* ktp = kt + (size_t)(b*NH+h)*DQ*TT;
  const float* ebp = embt + (size_t)h*DQ*NREL;
  float lg[4];
  #pragma unroll
  for (int c=0;c<4;++c) lg[c] = -1e30f;
  #pragma unroll
  for (int c=0;c<4;++c) {
    int jj = c*64 + lane;
    if (jj < nw) {
      int j = wlo + jj;
      int e = j - i + WIN;                  // 0..198
      float dot = 0.f;
      for (int a = 0; a < DQ; ++a)
        dot = fmaf(sq[a], ktp[a*TT + j] + ebp[a*NREL + e], dot);
      lg[c] = dot;
    }
  }
  float m = fmaxf(fmaxf(lg[0],lg[1]), fmaxf(lg[2],lg[3]));
  #pragma unroll
  for (int off=32; off; off>>=1) m = fmaxf(m, __shfl_xor(m, off));
  float s = 0.f;
  #pragma unroll
  for (int c=0;c<4;++c) {
    int jj = c*64 + lane;
    float p = 0.f;
    if (jj < nw) { p = __expf(lg[c]-m); s += p; }
    sp[jj] = p;
  }
  #pragma unroll
  for (int off=32; off; off>>=1) s += __shfl_xor(s, off);
  float inv = 1.f / s;
  __syncthreads();
  for (int a = lane; a < DQ; a += 64) {
    float acc = 0.f;
    for (int jj = 0; jj < nw; ++jj)
      acc = fmaf(sp[jj], v[((size_t)(wlo+jj)*BB + b)*DM + h*DQ + a], acc);
    o[((size_t)i*BB + b)*DM + h*DQ + a] = acc * inv;
  }
}

// ---------------- fused residual + LayerNorm (in-place on src) ----------------
__global__ __launch_bounds__(256)
void k_ln_residual(float* __restrict__ src, const float* __restrict__ res,
                   const float* __restrict__ g, const float* __restrict__ bta) {
  __shared__ float red[4];
  int n = blockIdx.x;
  float x[3];
  float s = 0.f;
  #pragma unroll
  for (int u=0;u<3;++u) {
    int d = u*256 + threadIdx.x;
    x[u] = src[(size_t)n*DM + d] + res[(size_t)n*DM + d];
    s += x[u];
  }
  #pragma unroll
  for (int off=32; off; off>>=1) s += __shfl_xor(s, off);
  if ((threadIdx.x & 63) == 0) red[threadIdx.x>>6] = s;
  __syncthreads();
  float mu = (red[0]+red[1]+red[2]+red[3]) * (1.f/DM);
  __syncthreads();
  float vs = 0.f;
  #pragma unroll
  for (int u=0;u<3;++u) { float dv = x[u]-mu; vs += dv*dv; }
  #pragma unroll
  for (int off=32; off; off>>=1) vs += __shfl_xor(vs, off);
  if ((threadIdx.x & 63) == 0) red[threadIdx.x>>6] = vs;
  __syncthreads();
  float rstd = rsqrtf((red[0]+red[1]+red[2]+red[3])*(1.f/DM) + 1e-5f);
  #pragma unroll
  for (int u=0;u<3;++u) {
    int d = u*256 + threadIdx.x;
    src[(size_t)n*DM + d] = (x[u]-mu)*rstd*g[d] + bta[d];
  }
}

extern "C" void kernel_launch(void* const* d_in, const int* in_sizes, int n_in,
                              void* d_out, int out_size, void* d_ws, size_t ws_size,
                              hipStream_t stream) {
  const float* x    = (const float*)d_in[0];
  const float* wq   = (const float*)d_in[1];
  const float* wk   = (const float*)d_in[2];
  const float* wv   = (const float*)d_in[3];
  const float* wo   = (const float*)d_in[4];
  const float* remb = (const float*)d_in[5];
  const float* ff1w = (const float*)d_in[6];
  const float* ff1b = (const float*)d_in[7];
  const float* ff2w = (const float*)d_in[8];
  const float* ff2b = (const float*)d_in[9];
  const float* ln1g = (const float*)d_in[10];
  const float* ln1b = (const float*)d_in[11];
  const float* ln2g = (const float*)d_in[12];
  const float* ln2b = (const float*)d_in[13];
  const float* wout = (const float*)d_in[14];
  const float* bout = (const float*)d_in[15];
  float* out = (float*)d_out;

  float* w = (float*)d_ws;
  size_t off = 0;
  float* src = w + off; off += (size_t)NTOK*DM;
  float* qb  = w + off; off += (size_t)NTOK*DM;   // hb aliases qb..ktb (4*NTOK*DM == NTOK*DFF)
  float* kb  = w + off; off += (size_t)NTOK*DM;
  float* vb  = w + off; off += (size_t)NTOK*DM;
  float* ktb = w + off; off += (size_t)NTOK*DM;
  float* ob  = w + off; off += (size_t)NTOK*DM;
  float* tmp = w + off; off += (size_t)NTOK*DM;
  float* hb  = qb;                                 // dead by the time FF runs
  float* wqt = w + off; off += (size_t)DM*DM;
  float* wkt = w + off; off += (size_t)DM*DM;
  float* wvt = w + off; off += (size_t)DM*DM;
  float* wot = w + off; off += (size_t)DM*DM;
  float* ebt = w + off; off += (size_t)NH*DQ*NREL;
  (void)off; (void)ws_size; (void)in_sizes; (void)n_in; (void)out_size;

  const float qscale = 0.10206207261596577f;  // 1/sqrt(96)
  dim3 b256(256);

  k_transpose_in<<<dim3(NTOK), b256, 0, stream>>>(x, src);

  for (int l = 0; l < NL; ++l) {
    k_transform_qkv<<<dim3((DM*DM+255)/256), b256, 0, stream>>>(
        wq + (size_t)l*DM*DM, wk + (size_t)l*DM*DM, wv + (size_t)l*DM*DM, wqt, wkt, wvt);
    k_transpose_wo<<<dim3((DM*DM+255)/256), b256, 0, stream>>>(wo + (size_t)l*DM*DM, wot);
    k_transpose_emb<<<dim3((NH*DQ*NREL+255)/256), b256, 0, stream>>>(
        remb + (size_t)l*NH*NREL*DQ, ebt);

    k_gemm_nt<64,64,16,4,4,false,false><<<dim3(DM/64, NTOK/64), b256, 0, stream>>>(
        src, wqt, nullptr, qb, NTOK, DM, DM, qscale);
    k_gemm_nt<64,64,16,4,4,false,false><<<dim3(DM/64, NTOK/64), b256, 0, stream>>>(
        src, wkt, nullptr, kb, NTOK, DM, DM, 1.f);
    k_gemm_nt<64,64,16,4,4,false,false><<<dim3(DM/64, NTOK/64), b256, 0, stream>>>(
        src, wvt, nullptr, vb, NTOK, DM, DM, 1.f);

    k_transpose_k<<<dim3((BB*NH*DQ*TT)/256), b256, 0, stream>>>(kb, ktb);

    k_attn<<<dim3(BB*NH*TT), dim3(64), 0, stream>>>(qb, ktb, vb, ebt, ob);

    k_gemm_nt<64,64,16,4,4,false,false><<<dim3(DM/64, NTOK/64), b256, 0, stream>>>(
        ob, wot, nullptr, tmp, NTOK, DM, DM, 1.f);
    k_ln_residual<<<dim3(NTOK), b256, 0, stream>>>(src, tmp, ln1g + (size_t)l*DM, ln1b + (size_t)l*DM);

    k_gemm_nt<128,128,16,8,8,true,false><<<dim3(DFF/128, NTOK/128), b256, 0, stream>>>(
        src, ff1w + (size_t)l*DFF*DM, ff1b + (size_t)l*DFF, hb, NTOK, DFF, DM, 1.f);
    k_gemm_nt<128,64,16,8,4,false,false><<<dim3(DM/64, NTOK/128), b256, 0, stream>>>(
        hb, ff2w + (size_t)l*DM*DFF, ff2b + (size_t)l*DM, tmp, NTOK, DM, DFF, 1.f);
    k_ln_residual<<<dim3(NTOK), b256, 0, stream>>>(src, tmp, ln2g + (size_t)l*DM, ln2b + (size_t)l*DM);
  }

  k_gemm_nt<64,64,16,4,4,false,true><<<dim3((ODIM+63)/64, NTOK/64), b256, 0, stream>>>(
      src, wout, bout, out, NTOK, ODIM, DM, 1.f);
}

// Round 2
// 3708.963 us; speedup vs baseline: 2.2187x; 2.2187x over previous
//
#include <hip/hip_runtime.h>
#include <hip/hip_bf16.h>
#include <math.h>

#define NL   6
#define DM   768
#define NH   8
#define DQ   96
#define DFF  3072
#define BB   8
#define TT   512
#define NTOK (BB*TT)      // 4096 tokens
#define NREL 201
#define WIN  99
#define ODIM 80
#define NQKV 2304         // fused q|k|v columns

typedef __attribute__((ext_vector_type(8))) short v8s;
typedef __attribute__((ext_vector_type(4))) float v4f;

// ---------------- input transpose: x(B,T,D) -> src(token n=t*8+b, D) fp32 + bf16 ----------------
__global__ void k_transpose_in(const float* __restrict__ x, float* __restrict__ src,
                               __hip_bfloat16* __restrict__ srcb) {
  int n = blockIdx.x;               // n = t*8 + b
  int t = n >> 3, b = n & 7;
  const float* xi = x + ((size_t)b*TT + t)*DM;
  for (int d = threadIdx.x; d < DM; d += blockDim.x) {
    float v = xi[d];
    src[(size_t)n*DM + d] = v;
    srcb[(size_t)n*DM + d] = __float2bfloat16(v);
  }
}

// ---------------- weight conversions (per layer) ----------------
// wq/wk/wv[h][f][a] -> fused qkvwb[n][f] bf16, n = part*768 + h*96+a; qscale folded into q part.
__global__ void k_conv_qkvw(const float* __restrict__ wq, const float* __restrict__ wk,
                            const float* __restrict__ wv, __hip_bfloat16* __restrict__ o) {
  int idx = blockIdx.x*256 + threadIdx.x;     // over NQKV*DM, f fastest
  if (idx >= NQKV*DM) return;
  int f = idx % DM, n = idx / DM;
  int part = n / DM, c = n % DM;
  int h = c / DQ, a = c % DQ;
  size_t si = ((size_t)h*DM + f)*DQ + a;
  float v = (part == 0) ? wq[si]*0.10206207261596577f : (part == 1 ? wk[si] : wv[si]);
  o[idx] = __float2bfloat16(v);
}

// wo[r=h*96+a][d] -> wob[d][r] bf16
__global__ void k_conv_wo(const float* __restrict__ wo, __hip_bfloat16* __restrict__ o) {
  int idx = blockIdx.x*256 + threadIdx.x;
  if (idx >= DM*DM) return;
  int r = idx % DM, d = idx / DM;
  o[idx] = __float2bfloat16(wo[(size_t)r*DM + d]);
}

// plain fp32 -> bf16 cast (ff weights are already NT layout)
__global__ void k_cast(const float* __restrict__ in, __hip_bfloat16* __restrict__ o, int n) {
  int idx = blockIdx.x*256 + threadIdx.x;
  if (idx < n) o[idx] = __float2bfloat16(in[idx]);
}

// wout (80,768) -> woutb (128,768) bf16, zero-padded rows
__global__ void k_conv_wout(const float* __restrict__ wout, __hip_bfloat16* __restrict__ o) {
  int idx = blockIdx.x*256 + threadIdx.x;     // over 128*DM
  if (idx >= 128*DM) return;
  int n = idx / DM, f = idx % DM;
  o[idx] = __float2bfloat16(n < ODIM ? wout[(size_t)n*DM + f] : 0.f);
}

// emb[h][e][a] -> embt[h][a][e] fp32
__global__ void k_transpose_emb(const float* __restrict__ emb, float* __restrict__ embt) {
  int idx = blockIdx.x*256 + threadIdx.x;     // over NH*DQ*NREL, e fastest
  if (idx >= NH*DQ*NREL) return;
  int e = idx % NREL; int a = (idx / NREL) % DQ; int h = idx / (NREL*DQ);
  embt[idx] = emb[((size_t)h*NREL + e)*DQ + a];
}

// qkv(n, 2304) k-part -> kt(b,h,a,t) fp32
__global__ void k_transpose_k(const float* __restrict__ qkv, float* __restrict__ kt) {
  int idx = blockIdx.x*256 + threadIdx.x;     // over BB*NH*DQ*TT, t fastest
  if (idx >= BB*NH*DQ*TT) return;
  int t = idx & (TT-1);
  int r = idx >> 9;                 // (b*8+h)*96 + a
  int a = r % DQ;
  int bh = r / DQ;
  int h = bh & (NH-1), b = bh >> 3;
  kt[idx] = qkv[((size_t)t*BB + b)*NQKV + DM + h*DQ + a];
}

// ---------------- bf16 MFMA GEMM: C[M,N] = A[M,K] * Bt[N,K]^T ----------------
// 128x128 tile, 4 waves x (64x64 via 4x4 mfma_f32_16x16x32_bf16), BK=64,
// global_load_lds width-16 staging, XOR chunk swizzle (on the GLOBAL fetch
// address -- LDS dest stays lane-linear per the m104/m108 constraint).
template<bool RELU, bool BF16OUT, bool PERM>
__global__ __launch_bounds__(256)
void k_mfma_gemm(const __hip_bfloat16* __restrict__ A, const __hip_bfloat16* __restrict__ Bt,
                 const float* __restrict__ bias, void* __restrict__ Cv,
                 int K, int Nvalid, int ldc) {
  __shared__ __align__(16) short As[128*64];   // row-major, 64 bf16 (=128B) per row
  __shared__ __align__(16) short Bs[128*64];
  const int tid = threadIdx.x;
  const int m0 = blockIdx.y*128, n0 = blockIdx.x*128;
  const int lane = tid & 63, w = tid >> 6;
  const int wm = (w >> 1)*64, wn = (w & 1)*64;
  const int mr = lane & 15, q4 = lane >> 4;
  const short* Ag = (const short*)A;
  const short* Bg = (const short*)Bt;
  const v4f zero = {0.f, 0.f, 0.f, 0.f};
  v4f acc[4][4];
  #pragma unroll
  for (int i=0;i<4;++i)
    #pragma unroll
    for (int j=0;j<4;++j) acc[i][j] = zero;

  for (int k0 = 0; k0 < K; k0 += 64) {
    #pragma unroll
    for (int s = 0; s < 4; ++s) {
      int cid = s*256 + tid;
      int row = cid >> 3;
      int c = (cid & 7) ^ (row & 7);          // swizzled global chunk
      __builtin_amdgcn_global_load_lds(
        (const __attribute__((address_space(1))) void*)(Ag + (size_t)(m0+row)*K + k0 + c*8),
        (__attribute__((address_space(3))) void*)(As + cid*8), 16, 0, 0);
      __builtin_amdgcn_global_load_lds(
        (const __attribute__((address_space(1))) void*)(Bg + (size_t)(n0+row)*K + k0 + c*8),
        (__attribute__((address_space(3))) void*)(Bs + cid*8), 16, 0, 0);
    }
    __syncthreads();
    #pragma unroll
    for (int kh = 0; kh < 2; ++kh) {
      int pos = (kh*4 + q4) ^ (mr & 7);       // swizzled LDS chunk position
      v8s af[4], bf[4];
      #pragma unroll
      for (int i=0;i<4;++i) af[i] = *(const v8s*)(As + (wm + i*16 + mr)*64 + pos*8);
      #pragma unroll
      for (int j=0;j<4;++j) bf[j] = *(const v8s*)(Bs + (wn + j*16 + mr)*64 + pos*8);
      #pragma unroll
      for (int i=0;i<4;++i)
        #pragma unroll
        for (int j=0;j<4;++j)
          acc[i][j] = __builtin_amdgcn_mfma_f32_16x16x32_bf16(af[i], bf[j], acc[i][j], 0, 0, 0);
    }
    __syncthreads();
  }

  // epilogue: C/D layout col=lane&15, row=q4*4+reg (m89/m91-verified)
  #pragma unroll
  for (int j=0;j<4;++j) {
    int col = n0 + wn + j*16 + mr;
    if (col < Nvalid) {
      float bv = bias ? bias[col] : 0.f;
      #pragma unroll
      for (int i=0;i<4;++i) {
        #pragma unroll
        for (int r=0;r<4;++r) {
          int m = m0 + wm + i*16 + q4*4 + r;
          float val = acc[i][j][r] + bv;
          if (RELU) val = fmaxf(val, 0.f);
          int row = PERM ? ((m & 7)*TT + (m >> 3)) : m;   // token t*8+b -> b*512+t
          if (BF16OUT) ((__hip_bfloat16*)Cv)[(size_t)row*ldc + col] = __float2bfloat16(val);
          else         ((float*)Cv)[(size_t)row*ldc + col] = val;
        }
      }
    }
  }
}

// ---------------- banded attention: one wave per (b,h,query) ----------------
// window |j-i|<=99 is exact: out-of-band logits get -1e8 in the reference -> exp underflows to 0.
__global__ __launch_bounds__(64)
void k_attn(const float* __restrict__ qkv,  // (n, 2304): q|k|v
            const float* __restrict__ kt,   // (b,h,a,t)
            const float* __restrict__ embt, // (h,a,e)
            __hip_bfloat16* __restrict__ o) { // (n, 768) bf16
  int gid = blockIdx.x;
  int i = gid & (TT-1);
  int h = (gid >> 9) & (NH-1);
  int b = gid >> 12;
  int lane = threadIdx.x;
  int wlo = max(i-WIN, 0), whi = min(i+WIN, TT-1);
  int nw = whi - wlo + 1;                   // 100..199
  __shared__ float sq[DQ];
  __shared__ float sp[256];
  for (int a = lane; a < DQ; a += 64)
    sq[a] = qkv[((size_t)i*BB + b)*NQKV + h*DQ + a];
  __syncthreads();
  const float* ktp = kt + (size_t)(b*NH+h)*DQ*TT;
  const float* ebp = embt + (size_t)h*DQ*NREL;
  float lg[4];
  #pragma unroll
  for (int c=0;c<4;++c) lg[c] = -1e30f;
  #pragma unroll
  for (int c=0;c<4;++c) {
    int jj = c*64 + lane;
    if (jj < nw) {
      int j = wlo + jj;
      int e = j - i + WIN;                  // 0..198
      float dot = 0.f;
      for (int a = 0; a < DQ; ++a)
        dot = fmaf(sq[a], ktp[a*TT + j] + ebp[a*NREL + e], dot);
      lg[c] = dot;
    }
  }
  float m = fmaxf(fmaxf(lg[0],lg[1]), fmaxf(lg[2],lg[3]));
  #pragma unroll
  for (int off=32; off; off>>=1) m = fmaxf(m, __shfl_xor(m, off));
  float s = 0.f;
  #pragma unroll
  for (int c=0;c<4;++c) {
    int jj = c*64 + lane;
    float p = 0.f;
    if (jj < nw) { p = __expf(lg[c]-m); s += p; }
    sp[jj] = p;
  }
  #pragma unroll
  for (int off=32; off; off>>=1) s += __shfl_xor(s, off);
  float inv = 1.f / s;
  __syncthreads();
  for (int a = lane; a < DQ; a += 64) {
    float acc = 0.f;
    for (int jj = 0; jj < nw; ++jj)
      acc = fmaf(sp[jj], qkv[((size_t)(wlo+jj)*BB + b)*NQKV + 2*DM + h*DQ + a], acc);
    o[((size_t)i*BB + b)*DM + h*DQ + a] = __float2bfloat16(acc * inv);
  }
}

// ---------------- fused residual + LayerNorm (in-place on src, + bf16 copy) ----------------
__global__ __launch_bounds__(256)
void k_ln_residual(float* __restrict__ src, const float* __restrict__ res,
                   const float* __restrict__ g, const float* __restrict__ bta,
                   __hip_bfloat16* __restrict__ srcb) {
  __shared__ float red[4];
  int n = blockIdx.x;
  float x[3];
  float s = 0.f;
  #pragma unroll
  for (int u=0;u<3;++u) {
    int d = u*256 + threadIdx.x;
    x[u] = src[(size_t)n*DM + d] + res[(size_t)n*DM + d];
    s += x[u];
  }
  #pragma unroll
  for (int off=32; off; off>>=1) s += __shfl_xor(s, off);
  if ((threadIdx.x & 63) == 0) red[threadIdx.x>>6] = s;
  __syncthreads();
  float mu = (red[0]+red[1]+red[2]+red[3]) * (1.f/DM);
  __syncthreads();
  float vs = 0.f;
  #pragma unroll
  for (int u=0;u<3;++u) { float dv = x[u]-mu; vs += dv*dv; }
  #pragma unroll
  for (int off=32; off; off>>=1) vs += __shfl_xor(vs, off);
  if ((threadIdx.x & 63) == 0) red[threadIdx.x>>6] = vs;
  __syncthreads();
  float rstd = rsqrtf((red[0]+red[1]+red[2]+red[3])*(1.f/DM) + 1e-5f);
  #pragma unroll
  for (int u=0;u<3;++u) {
    int d = u*256 + threadIdx.x;
    float v = (x[u]-mu)*rstd*g[d] + bta[d];
    src[(size_t)n*DM + d] = v;
    srcb[(size_t)n*DM + d] = __float2bfloat16(v);
  }
}

extern "C" void kernel_launch(void* const* d_in, const int* in_sizes, int n_in,
                              void* d_out, int out_size, void* d_ws, size_t ws_size,
                              hipStream_t stream) {
  const float* x    = (const float*)d_in[0];
  const float* wq   = (const float*)d_in[1];
  const float* wk   = (const float*)d_in[2];
  const float* wv   = (const float*)d_in[3];
  const float* wo   = (const float*)d_in[4];
  const float* remb = (const float*)d_in[5];
  const float* ff1w = (const float*)d_in[6];
  const float* ff1b = (const float*)d_in[7];
  const float* ff2w = (const float*)d_in[8];
  const float* ff2b = (const float*)d_in[9];
  const float* ln1g = (const float*)d_in[10];
  const float* ln1b = (const float*)d_in[11];
  const float* ln2g = (const float*)d_in[12];
  const float* ln2b = (const float*)d_in[13];
  const float* wout = (const float*)d_in[14];
  const float* bout = (const float*)d_in[15];
  float* out = (float*)d_out;

  float* w = (float*)d_ws;
  size_t off = 0;
  float* src = w + off;                               off += (size_t)NTOK*DM;
  __hip_bfloat16* srcb = (__hip_bfloat16*)(w + off);  off += (size_t)NTOK*DM/2;
  float* qkv = w + off;                               off += (size_t)NTOK*NQKV; // also hb (bf16 NTOK*DFF fits)
  float* ktb = w + off;                               off += (size_t)NTOK*DM;   // also tmp (sequential reuse)
  float* ebt = w + off;                               off += (size_t)NH*DQ*NREL;
  __hip_bfloat16* qkvwb = (__hip_bfloat16*)(w + off); off += (size_t)NQKV*DM/2;
  __hip_bfloat16* wob   = (__hip_bfloat16*)(w + off); off += (size_t)DM*DM/2;
  __hip_bfloat16* ff1wb = (__hip_bfloat16*)(w + off); off += (size_t)DFF*DM/2;
  __hip_bfloat16* ff2wb = (__hip_bfloat16*)(w + off); off += (size_t)DM*DFF/2;
  __hip_bfloat16* woutb = (__hip_bfloat16*)(w + off); off += (size_t)128*DM/2;
  __hip_bfloat16* hb  = (__hip_bfloat16*)qkv;   // qkv dead once attention finishes
  __hip_bfloat16* obb = srcb;                    // srcb dead after QKV GEMM, rewritten by LN1
  float* tmp = ktb;                              // ktb dead once attention finishes
  (void)off; (void)ws_size; (void)in_sizes; (void)n_in; (void)out_size;

  dim3 b256(256);

  k_transpose_in<<<dim3(NTOK), b256, 0, stream>>>(x, src, srcb);

  for (int l = 0; l < NL; ++l) {
    k_conv_qkvw<<<dim3((NQKV*DM+255)/256), b256, 0, stream>>>(
        wq + (size_t)l*DM*DM, wk + (size_t)l*DM*DM, wv + (size_t)l*DM*DM, qkvwb);
    k_conv_wo<<<dim3((DM*DM+255)/256), b256, 0, stream>>>(wo + (size_t)l*DM*DM, wob);
    k_cast<<<dim3((DFF*DM+255)/256), b256, 0, stream>>>(ff1w + (size_t)l*DFF*DM, ff1wb, DFF*DM);
    k_cast<<<dim3((DM*DFF+255)/256), b256, 0, stream>>>(ff2w + (size_t)l*DM*DFF, ff2wb, DM*DFF);
    k_transpose_emb<<<dim3((NH*DQ*NREL+255)/256), b256, 0, stream>>>(
        remb + (size_t)l*NH*NREL*DQ, ebt);

    // fused QKV: (4096 x 2304) = srcb (4096x768) * qkvwb^T
    k_mfma_gemm<false,false,false><<<dim3(NQKV/128, NTOK/128), b256, 0, stream>>>(
        srcb, qkvwb, nullptr, qkv, DM, NQKV, NQKV);

    k_transpose_k<<<dim3((BB*NH*DQ*TT)/256), b256, 0, stream>>>(qkv, ktb);
    k_attn<<<dim3(BB*NH*TT), dim3(64), 0, stream>>>(qkv, ktb, ebt, obb);

    // O-proj: tmp = obb * wob^T
    k_mfma_gemm<false,false,false><<<dim3(DM/128, NTOK/128), b256, 0, stream>>>(
        obb, wob, nullptr, tmp, DM, DM, DM);
    k_ln_residual<<<dim3(NTOK), b256, 0, stream>>>(src, tmp, ln1g + (size_t)l*DM, ln1b + (size_t)l*DM, srcb);

    // FF1: hb = relu(srcb * ff1wb^T + b), bf16 out
    k_mfma_gemm<true,true,false><<<dim3(DFF/128, NTOK/128), b256, 0, stream>>>(
        srcb, ff1wb, ff1b + (size_t)l*DFF, hb, DM, DFF, DFF);
    // FF2: tmp = hb * ff2wb^T + b
    k_mfma_gemm<false,false,false><<<dim3(DM/128, NTOK/128), b256, 0, stream>>>(
        hb, ff2wb, ff2b + (size_t)l*DM, tmp, DFF, DM, DM);
    k_ln_residual<<<dim3(NTOK), b256, 0, stream>>>(src, tmp, ln2g + (size_t)l*DM, ln2b + (size_t)l*DM, srcb);
  }

  k_conv_wout<<<dim3((128*DM+255)/256), b256, 0, stream>>>(wout, woutb);
  k_mfma_gemm<false,false,true><<<dim3(1, NTOK/128), b256, 0, stream>>>(
      srcb, woutb, bout, out, DM, ODIM, ODIM);
}

// Round 3
// 1339.122 us; speedup vs baseline: 6.1451x; 2.7697x over previous
//
#include <hip/hip_runtime.h>
#include <hip/hip_bf16.h>
#include <math.h>

#define NL   6
#define DM   768
#define NH   8
#define DQ   96
#define DFF  3072
#define BB   8
#define TT   512
#define NTOK (BB*TT)      // 4096 tokens
#define NREL 201
#define WIN  99
#define ODIM 80
#define NQKV 2304         // fused q|k|v columns
#define RELD 208          // padded e-dim of REL buffer

typedef __attribute__((ext_vector_type(8))) short v8s;
typedef __attribute__((ext_vector_type(4))) float v4f;

static __device__ __forceinline__ short bf16bits(float x) {
  __hip_bfloat16 h = __float2bfloat16(x);
  return *(short*)&h;
}

// ---------------- input transpose: x(B,T,D) -> src(token n=t*8+b, D) fp32 + bf16 ----------------
__global__ void k_transpose_in(const float* __restrict__ x, float* __restrict__ src,
                               __hip_bfloat16* __restrict__ srcb) {
  int n = blockIdx.x;               // n = t*8 + b
  int t = n >> 3, b = n & 7;
  const float* xi = x + ((size_t)b*TT + t)*DM;
  for (int d = threadIdx.x; d < DM; d += blockDim.x) {
    float v = xi[d];
    src[(size_t)n*DM + d] = v;
    srcb[(size_t)n*DM + d] = __float2bfloat16(v);
  }
}

// wq/wk/wv[h][f][a] -> fused qkvwb[n][f] bf16, n = part*768 + h*96+a; qscale folded into q part.
__global__ void k_conv_qkvw(const float* __restrict__ wq, const float* __restrict__ wk,
                            const float* __restrict__ wv, __hip_bfloat16* __restrict__ o) {
  int idx = blockIdx.x*256 + threadIdx.x;     // over NQKV*DM, f fastest
  if (idx >= NQKV*DM) return;
  int f = idx % DM, n = idx / DM;
  int part = n / DM, c = n % DM;
  int h = c / DQ, a = c % DQ;
  size_t si = ((size_t)h*DM + f)*DQ + a;
  float v = (part == 0) ? wq[si]*0.10206207261596577f : (part == 1 ? wk[si] : wv[si]);
  o[idx] = __float2bfloat16(v);
}

// wo[r=h*96+a][d] -> wob[d][r] bf16
__global__ void k_conv_wo(const float* __restrict__ wo, __hip_bfloat16* __restrict__ o) {
  int idx = blockIdx.x*256 + threadIdx.x;
  if (idx >= DM*DM) return;
  int r = idx % DM, d = idx / DM;
  o[idx] = __float2bfloat16(wo[(size_t)r*DM + d]);
}

// plain fp32 -> bf16 cast
__global__ void k_cast(const float* __restrict__ in, __hip_bfloat16* __restrict__ o, int n) {
  int idx = blockIdx.x*256 + threadIdx.x;
  if (idx < n) o[idx] = __float2bfloat16(in[idx]);
}

// wout (80,768) -> woutb (128,768) bf16, zero-padded rows
__global__ void k_conv_wout(const float* __restrict__ wout, __hip_bfloat16* __restrict__ o) {
  int idx = blockIdx.x*256 + threadIdx.x;     // over 128*DM
  if (idx >= 128*DM) return;
  int n = idx / DM, f = idx % DM;
  o[idx] = __float2bfloat16(n < ODIM ? wout[(size_t)n*DM + f] : 0.f);
}

// ---------------- generalized bf16 MFMA GEMM: C[M,N] = A[M,K] * Bt[N,K]^T ----------------
// 4 waves; tile BM x BN; wave tile WM x WN; BK=64; global_load_lds width-16; XOR chunk swizzle.
template<int BM, int BN, int WM, int WN, bool RELU, bool BF16OUT, bool PERM>
__global__ __launch_bounds__(256)
void k_mfma_gemm(const __hip_bfloat16* __restrict__ A, const __hip_bfloat16* __restrict__ Bt,
                 const float* __restrict__ bias, void* __restrict__ Cv,
                 int K, int Nvalid, int ldc) {
  constexpr int NWN = BN/WN;
  constexpr int FM = WM/16, FN = WN/16;
  __shared__ __align__(16) short As[BM*64];
  __shared__ __align__(16) short Bs[BN*64];
  const int tid = threadIdx.x;
  const int m0 = blockIdx.y*BM, n0 = blockIdx.x*BN;
  const int lane = tid & 63, w = tid >> 6;
  const int wm = (w / NWN)*WM, wn = (w % NWN)*WN;
  const int mr = lane & 15, q4 = lane >> 4;
  const short* Ag = (const short*)A;
  const short* Bg = (const short*)Bt;
  const v4f zero = {0.f, 0.f, 0.f, 0.f};
  v4f acc[FM][FN];
  #pragma unroll
  for (int i=0;i<FM;++i)
    #pragma unroll
    for (int j=0;j<FN;++j) acc[i][j] = zero;

  for (int k0 = 0; k0 < K; k0 += 64) {
    #pragma unroll
    for (int s = 0; s < (BM*8)/256; ++s) {
      int cid = s*256 + tid;
      int row = cid >> 3;
      int c = (cid & 7) ^ (row & 7);
      __builtin_amdgcn_global_load_lds(
        (const __attribute__((address_space(1))) void*)(Ag + (size_t)(m0+row)*K + k0 + c*8),
        (__attribute__((address_space(3))) void*)(As + cid*8), 16, 0, 0);
    }
    #pragma unroll
    for (int s = 0; s < (BN*8)/256; ++s) {
      int cid = s*256 + tid;
      int row = cid >> 3;
      int c = (cid & 7) ^ (row & 7);
      __builtin_amdgcn_global_load_lds(
        (const __attribute__((address_space(1))) void*)(Bg + (size_t)(n0+row)*K + k0 + c*8),
        (__attribute__((address_space(3))) void*)(Bs + cid*8), 16, 0, 0);
    }
    __syncthreads();
    #pragma unroll
    for (int kh = 0; kh < 2; ++kh) {
      int pos = (kh*4 + q4) ^ (mr & 7);
      v8s af[FM], bf[FN];
      #pragma unroll
      for (int i=0;i<FM;++i) af[i] = *(const v8s*)(As + (wm + i*16 + mr)*64 + pos*8);
      #pragma unroll
      for (int j=0;j<FN;++j) bf[j] = *(const v8s*)(Bs + (wn + j*16 + mr)*64 + pos*8);
      #pragma unroll
      for (int i=0;i<FM;++i)
        #pragma unroll
        for (int j=0;j<FN;++j)
          acc[i][j] = __builtin_amdgcn_mfma_f32_16x16x32_bf16(af[i], bf[j], acc[i][j], 0, 0, 0);
    }
    __syncthreads();
  }

  #pragma unroll
  for (int j=0;j<FN;++j) {
    int col = n0 + wn + j*16 + mr;
    if (col < Nvalid) {
      float bv = bias ? bias[col] : 0.f;
      #pragma unroll
      for (int i=0;i<FM;++i) {
        #pragma unroll
        for (int r=0;r<4;++r) {
          int m = m0 + wm + i*16 + q4*4 + r;
          float val = acc[i][j][r] + bv;
          if (RELU) val = fmaxf(val, 0.f);
          int row = PERM ? ((m & 7)*TT + (m >> 3)) : m;   // token t*8+b -> b*512+t
          if (BF16OUT) ((__hip_bfloat16*)Cv)[(size_t)row*ldc + col] = __float2bfloat16(val);
          else         ((float*)Cv)[(size_t)row*ldc + col] = val;
        }
      }
    }
  }
}

// ---------------- REL precompute: REL[h][n][e] = q_n . emb_h[e], fp32 out ----------------
// grid (4 etiles, 64 mtiles, 8 h); block 256 (4 waves); K=96 (no K-loop).
__global__ __launch_bounds__(256)
void k_rel_gemm(const __hip_bfloat16* __restrict__ qkvb,
                const __hip_bfloat16* __restrict__ embb,
                float* __restrict__ rel) {
  const int e0 = blockIdx.x*64, m0 = blockIdx.y*64, h = blockIdx.z;
  const int tid = threadIdx.x, lane = tid & 63, w = tid >> 6;
  const int l15 = lane & 15, q4 = lane >> 4;
  __shared__ __align__(16) short As[64*104];
  __shared__ __align__(16) short Bs[64*104];
  const short* qg = (const short*)qkvb;
  const short* eg = (const short*)embb;
  {
    int row = tid >> 2;
    const short* sa = qg + (size_t)(m0+row)*NQKV + h*DQ;
    int er = e0 + row; if (er > 200) er = 200;
    const short* sb = eg + ((size_t)h*NREL + er)*DQ;
    short* da = As + row*104;
    short* db = Bs + row*104;
    #pragma unroll
    for (int c = 0; c < 3; ++c) {
      int ch = (tid & 3)*3 + c;
      *(v8s*)(da + ch*8) = *(const v8s*)(sa + ch*8);
      *(v8s*)(db + ch*8) = *(const v8s*)(sb + ch*8);
    }
  }
  __syncthreads();
  const v4f zero = {0.f,0.f,0.f,0.f};
  v4f acc[4] = {zero, zero, zero, zero};
  #pragma unroll
  for (int ks = 0; ks < 3; ++ks) {
    v8s af = *(const v8s*)(As + (w*16 + l15)*104 + ks*32 + q4*8);
    #pragma unroll
    for (int f = 0; f < 4; ++f) {
      v8s bf = *(const v8s*)(Bs + (f*16 + l15)*104 + ks*32 + q4*8);
      acc[f] = __builtin_amdgcn_mfma_f32_16x16x32_bf16(af, bf, acc[f], 0, 0, 0);
    }
  }
  #pragma unroll
  for (int f = 0; f < 4; ++f) {
    int e = e0 + f*16 + l15;
    if (e < 2*WIN + 1) {
      #pragma unroll
      for (int r = 0; r < 4; ++r) {
        int n = m0 + w*16 + q4*4 + r;
        rel[((size_t)h*NTOK + n)*RELD + e] = acc[f][r];
      }
    }
  }
}

// ---------------- banded MFMA attention ----------------
// block: (qt, h, b) handles 64 queries; 4 waves, each owns a 16-row strip.
// key tiles kt0 = qlo + 64*c - 128, c=0..4 cover the +/-99 band exactly.
__global__ __launch_bounds__(256)
void k_attn_mfma(const __hip_bfloat16* __restrict__ qkvb,
                 const float* __restrict__ rel,
                 __hip_bfloat16* __restrict__ o) {
  const int qt = blockIdx.x, h = blockIdx.y, b = blockIdx.z;
  const int qlo = qt*64;
  const int tid = threadIdx.x, lane = tid & 63, w = tid >> 6;
  const int l15 = lane & 15, q4 = lane >> 4;
  __shared__ __align__(16) short Qs[64*104];
  __shared__ __align__(16) short Ks[64*104];
  __shared__ __align__(16) short Vt[96*72];
  __shared__ __align__(16) short Ps[64*72];
  const short* qg = (const short*)qkvb;

  // stage Q (64 rows x 96 bf16)
  {
    int row = tid >> 2;
    const short* src = qg + (size_t)((qlo+row)*8 + b)*NQKV + h*DQ;
    short* dst = Qs + row*104;
    #pragma unroll
    for (int c = 0; c < 3; ++c) {
      int ch = (tid & 3)*3 + c;
      *(v8s*)(dst + ch*8) = *(const v8s*)(src + ch*8);
    }
  }

  v4f sacc[5][4];
  const v4f neg = {-1e30f,-1e30f,-1e30f,-1e30f};
  #pragma unroll
  for (int kt=0;kt<5;++kt)
    #pragma unroll
    for (int f=0;f<4;++f) sacc[kt][f] = neg;

  const int i_row0 = qlo + w*16 + q4*4;   // + r

  // ---- phase 1: S = QK^T + REL (accumulators in registers) ----
  for (int kt = 0; kt < 5; ++kt) {
    int kt0 = qlo + kt*64 - 128;
    if (kt0 + 64 <= 0 || kt0 >= TT) continue;
    {
      int row = tid >> 2;
      int j = kt0 + row; j = j < 0 ? 0 : (j > TT-1 ? TT-1 : j);
      const short* src = qg + (size_t)(j*8 + b)*NQKV + DM + h*DQ;
      short* dst = Ks + row*104;
      #pragma unroll
      for (int c = 0; c < 3; ++c) {
        int ch = (tid & 3)*3 + c;
        *(v8s*)(dst + ch*8) = *(const v8s*)(src + ch*8);
      }
    }
    __syncthreads();
    // init acc from REL (exact band mask)
    #pragma unroll
    for (int f = 0; f < 4; ++f) {
      int j = kt0 + f*16 + l15;
      #pragma unroll
      for (int r = 0; r < 4; ++r) {
        int i = i_row0 + r;
        int d = j - i;
        float val = -1e30f;
        if (j >= 0 && j < TT && d >= -WIN && d <= WIN)
          val = rel[((size_t)h*NTOK + i*8 + b)*RELD + d + WIN];
        sacc[kt][f][r] = val;
      }
    }
    #pragma unroll
    for (int ks = 0; ks < 3; ++ks) {
      v8s af = *(const v8s*)(Qs + (w*16 + l15)*104 + ks*32 + q4*8);
      #pragma unroll
      for (int f = 0; f < 4; ++f) {
        v8s bf = *(const v8s*)(Ks + (f*16 + l15)*104 + ks*32 + q4*8);
        sacc[kt][f] = __builtin_amdgcn_mfma_f32_16x16x32_bf16(af, bf, sacc[kt][f], 0, 0, 0);
      }
    }
    __syncthreads();
  }

  // ---- phase 2: softmax in registers (rows partitioned by q4, cols by l15) ----
  float inv[4];
  #pragma unroll
  for (int r = 0; r < 4; ++r) {
    float m = -1e30f;
    #pragma unroll
    for (int kt=0;kt<5;++kt)
      #pragma unroll
      for (int f=0;f<4;++f) m = fmaxf(m, sacc[kt][f][r]);
    #pragma unroll
    for (int off=1; off<16; off<<=1) m = fmaxf(m, __shfl_xor(m, off));
    float l = 0.f;
    #pragma unroll
    for (int kt=0;kt<5;++kt)
      #pragma unroll
      for (int f=0;f<4;++f) {
        float p = __expf(sacc[kt][f][r] - m);
        sacc[kt][f][r] = p; l += p;
      }
    #pragma unroll
    for (int off=1; off<16; off<<=1) l += __shfl_xor(l, off);
    inv[r] = 1.f / l;
  }

  // ---- phase 3: O = P V ----
  v4f oacc[6];
  const v4f zero = {0.f,0.f,0.f,0.f};
  #pragma unroll
  for (int f=0;f<6;++f) oacc[f] = zero;
  for (int kt = 0; kt < 5; ++kt) {
    int kt0 = qlo + kt*64 - 128;
    if (kt0 + 64 <= 0 || kt0 >= TT) continue;
    // write P tile (unnormalized, bf16) in A-frag layout
    #pragma unroll
    for (int f=0;f<4;++f)
      #pragma unroll
      for (int r=0;r<4;++r)
        Ps[(w*16 + q4*4 + r)*72 + f*16 + l15] = bf16bits(sacc[kt][f][r]);
    // stage V transposed: Vt[a][j_local]
    {
      int j = kt0 + (tid >> 2);
      int jc = j < 0 ? 0 : (j > TT-1 ? TT-1 : j);
      const short* src = qg + (size_t)(jc*8 + b)*NQKV + 2*DM + h*DQ + (tid & 3)*24;
      union { v8s v[3]; short s[24]; } u;
      u.v[0] = *(const v8s*)(src);
      u.v[1] = *(const v8s*)(src + 8);
      u.v[2] = *(const v8s*)(src + 16);
      int a0 = (tid & 3)*24, jl = tid >> 2;
      #pragma unroll
      for (int t=0;t<24;++t) Vt[(a0+t)*72 + jl] = u.s[t];
    }
    __syncthreads();
    #pragma unroll
    for (int ks=0;ks<2;++ks) {
      v8s af = *(const v8s*)(Ps + (w*16 + l15)*72 + ks*32 + q4*8);
      #pragma unroll
      for (int f=0;f<6;++f) {
        v8s bf = *(const v8s*)(Vt + (f*16 + l15)*72 + ks*32 + q4*8);
        oacc[f] = __builtin_amdgcn_mfma_f32_16x16x32_bf16(af, bf, oacc[f], 0, 0, 0);
      }
    }
    __syncthreads();
  }

  // epilogue: normalize + store bf16
  #pragma unroll
  for (int f=0;f<6;++f)
    #pragma unroll
    for (int r=0;r<4;++r) {
      int i = i_row0 + r;
      o[(size_t)(i*8 + b)*DM + h*DQ + f*16 + l15] = __float2bfloat16(oacc[f][r] * inv[r]);
    }
}

// ---------------- fused residual + LayerNorm (in-place on src, + bf16 copy) ----------------
__global__ __launch_bounds__(256)
void k_ln_residual(float* __restrict__ src, const float* __restrict__ res,
                   const float* __restrict__ g, const float* __restrict__ bta,
                   __hip_bfloat16* __restrict__ srcb) {
  __shared__ float red[4];
  int n = blockIdx.x;
  float x[3];
  float s = 0.f;
  #pragma unroll
  for (int u=0;u<3;++u) {
    int d = u*256 + threadIdx.x;
    x[u] = src[(size_t)n*DM + d] + res[(size_t)n*DM + d];
    s += x[u];
  }
  #pragma unroll
  for (int off=32; off; off>>=1) s += __shfl_xor(s, off);
  if ((threadIdx.x & 63) == 0) red[threadIdx.x>>6] = s;
  __syncthreads();
  float mu = (red[0]+red[1]+red[2]+red[3]) * (1.f/DM);
  __syncthreads();
  float vs = 0.f;
  #pragma unroll
  for (int u=0;u<3;++u) { float dv = x[u]-mu; vs += dv*dv; }
  #pragma unroll
  for (int off=32; off; off>>=1) vs += __shfl_xor(vs, off);
  if ((threadIdx.x & 63) == 0) red[threadIdx.x>>6] = vs;
  __syncthreads();
  float rstd = rsqrtf((red[0]+red[1]+red[2]+red[3])*(1.f/DM) + 1e-5f);
  #pragma unroll
  for (int u=0;u<3;++u) {
    int d = u*256 + threadIdx.x;
    float v = (x[u]-mu)*rstd*g[d] + bta[d];
    src[(size_t)n*DM + d] = v;
    srcb[(size_t)n*DM + d] = __float2bfloat16(v);
  }
}

extern "C" void kernel_launch(void* const* d_in, const int* in_sizes, int n_in,
                              void* d_out, int out_size, void* d_ws, size_t ws_size,
                              hipStream_t stream) {
  const float* x    = (const float*)d_in[0];
  const float* wq   = (const float*)d_in[1];
  const float* wk   = (const float*)d_in[2];
  const float* wv   = (const float*)d_in[3];
  const float* wo   = (const float*)d_in[4];
  const float* remb = (const float*)d_in[5];
  const float* ff1w = (const float*)d_in[6];
  const float* ff1b = (const float*)d_in[7];
  const float* ff2w = (const float*)d_in[8];
  const float* ff2b = (const float*)d_in[9];
  const float* ln1g = (const float*)d_in[10];
  const float* ln1b = (const float*)d_in[11];
  const float* ln2g = (const float*)d_in[12];
  const float* ln2b = (const float*)d_in[13];
  const float* wout = (const float*)d_in[14];
  const float* bout = (const float*)d_in[15];
  float* out = (float*)d_out;

  float* wsp = (float*)d_ws;
  size_t off = 0;
  float* src  = wsp + off;                              off += (size_t)NTOK*DM;
  __hip_bfloat16* srcb  = (__hip_bfloat16*)(wsp + off); off += (size_t)NTOK*DM/2;
  __hip_bfloat16* qkvb  = (__hip_bfloat16*)(wsp + off); off += (size_t)NTOK*NQKV/2;
  float* rel  = wsp + off;                              off += (size_t)NH*NTOK*RELD;
  float* tmp  = wsp + off;                              off += (size_t)NTOK*DM;
  __hip_bfloat16* qkvwb = (__hip_bfloat16*)(wsp + off); off += (size_t)NQKV*DM/2;
  __hip_bfloat16* wob   = (__hip_bfloat16*)(wsp + off); off += (size_t)DM*DM/2;
  __hip_bfloat16* ff1wb = (__hip_bfloat16*)(wsp + off); off += (size_t)DFF*DM/2;
  __hip_bfloat16* ff2wb = (__hip_bfloat16*)(wsp + off); off += (size_t)DM*DFF/2;
  __hip_bfloat16* woutb = (__hip_bfloat16*)(wsp + off); off += (size_t)128*DM/2;
  __hip_bfloat16* embb  = (__hip_bfloat16*)(wsp + off); off += (size_t)NH*NREL*DQ/2 + 64;
  __hip_bfloat16* hb  = (__hip_bfloat16*)qkvb;  // FF1 out: qkvb+rel region is dead post-attention
  __hip_bfloat16* obb = srcb;                   // attention out: srcb dead until LN1 rewrites it
  (void)off; (void)ws_size; (void)in_sizes; (void)n_in; (void)out_size;

  dim3 b256(256);

  k_transpose_in<<<dim3(NTOK), b256, 0, stream>>>(x, src, srcb);

  for (int l = 0; l < NL; ++l) {
    k_conv_qkvw<<<dim3((NQKV*DM+255)/256), b256, 0, stream>>>(
        wq + (size_t)l*DM*DM, wk + (size_t)l*DM*DM, wv + (size_t)l*DM*DM, qkvwb);
    k_conv_wo<<<dim3((DM*DM+255)/256), b256, 0, stream>>>(wo + (size_t)l*DM*DM, wob);
    k_cast<<<dim3((DFF*DM+255)/256), b256, 0, stream>>>(ff1w + (size_t)l*DFF*DM, ff1wb, DFF*DM);
    k_cast<<<dim3((DM*DFF+255)/256), b256, 0, stream>>>(ff2w + (size_t)l*DM*DFF, ff2wb, DM*DFF);
    k_cast<<<dim3((NH*NREL*DQ+255)/256), b256, 0, stream>>>(remb + (size_t)l*NH*NREL*DQ,
                                                            embb, NH*NREL*DQ);

    // fused QKV (bf16 out): (4096 x 2304)
    k_mfma_gemm<128,128,64,64,false,true,false><<<dim3(NQKV/128, NTOK/128), b256, 0, stream>>>(
        srcb, qkvwb, nullptr, qkvb, DM, NQKV, NQKV);

    // REL[h][n][e] = q . emb
    k_rel_gemm<<<dim3(4, NTOK/64, NH), b256, 0, stream>>>(qkvb, embb, rel);

    // banded MFMA attention
    k_attn_mfma<<<dim3(TT/64, NH, BB), b256, 0, stream>>>(qkvb, rel, obb);

    // O-proj (64x128 tiles for occupancy): tmp = obb * wob^T
    k_mfma_gemm<64,128,64,32,false,false,false><<<dim3(DM/128, NTOK/64), b256, 0, stream>>>(
        obb, wob, nullptr, tmp, DM, DM, DM);
    k_ln_residual<<<dim3(NTOK), b256, 0, stream>>>(src, tmp, ln1g + (size_t)l*DM, ln1b + (size_t)l*DM, srcb);

    // FF1: hb = relu(srcb * ff1wb^T + b), bf16 out
    k_mfma_gemm<128,128,64,64,true,true,false><<<dim3(DFF/128, NTOK/128), b256, 0, stream>>>(
        srcb, ff1wb, ff1b + (size_t)l*DFF, hb, DM, DFF, DFF);
    // FF2: tmp = hb * ff2wb^T + b
    k_mfma_gemm<64,128,64,32,false,false,false><<<dim3(DM/128, NTOK/64), b256, 0, stream>>>(
        hb, ff2wb, ff2b + (size_t)l*DM, tmp, DFF, DM, DM);
    k_ln_residual<<<dim3(NTOK), b256, 0, stream>>>(src, tmp, ln2g + (size_t)l*DM, ln2b + (size_t)l*DM, srcb);
  }

  k_conv_wout<<<dim3((128*DM+255)/256), b256, 0, stream>>>(wout, woutb);
  k_mfma_gemm<64,128,64,32,false,false,true><<<dim3(1, NTOK/64), b256, 0, stream>>>(
      srcb, woutb, bout, out, DM, ODIM, ODIM);
}

// Round 4
// 1305.382 us; speedup vs baseline: 6.3039x; 1.0258x over previous
//
#include <hip/hip_runtime.h>
#include <hip/hip_bf16.h>
#include <math.h>

#define NL   6
#define DM   768
#define NH   8
#define DQ   96
#define DFF  3072
#define BB   8
#define TT   512
#define NTOK (BB*TT)      // 4096 tokens
#define NREL 201
#define WIN  99
#define ODIM 80
#define NQKV 2304         // fused q|k|v columns
#define RELD 208          // padded e-dim of REL buffer

typedef __attribute__((ext_vector_type(8))) short v8s;
typedef __attribute__((ext_vector_type(4))) float v4f;

static __device__ __forceinline__ short bf16bits(float x) {
  __hip_bfloat16 h = __float2bfloat16(x);
  return *(short*)&h;
}

// ---------------- input transpose: x(B,T,D) -> src(token n=t*8+b, D) fp32 + bf16 ----------------
__global__ void k_transpose_in(const float* __restrict__ x, float* __restrict__ src,
                               __hip_bfloat16* __restrict__ srcb) {
  int n = blockIdx.x;               // n = t*8 + b
  int t = n >> 3, b = n & 7;
  const float* xi = x + ((size_t)b*TT + t)*DM;
  for (int d = threadIdx.x; d < DM; d += blockDim.x) {
    float v = xi[d];
    src[(size_t)n*DM + d] = v;
    srcb[(size_t)n*DM + d] = __float2bfloat16(v);
  }
}

// ---------------- batched weight conversions (ALL layers upfront) ----------------
// wq/wk/wv[l][h][f][a] -> qkvwb[l][n][f] bf16, n = part*768 + h*96+a; qscale folded into q.
__global__ void k_conv_qkvw(const float* __restrict__ wq, const float* __restrict__ wk,
                            const float* __restrict__ wv, __hip_bfloat16* __restrict__ o) {
  size_t idx = (size_t)blockIdx.x*256 + threadIdx.x;   // over NL*NQKV*DM
  if (idx >= (size_t)NL*NQKV*DM) return;
  int f = idx % DM; size_t rest = idx / DM;
  int n = rest % NQKV; int l = rest / NQKV;
  int part = n / DM, c = n % DM;
  int h = c / DQ, a = c % DQ;
  size_t si = (size_t)l*DM*DM + ((size_t)h*DM + f)*DQ + a;
  float v = (part == 0) ? wq[si]*0.10206207261596577f : (part == 1 ? wk[si] : wv[si]);
  o[idx] = __float2bfloat16(v);
}

// wo[l][r=h*96+a][d] -> wob[l][d][r] bf16
__global__ void k_conv_wo(const float* __restrict__ wo, __hip_bfloat16* __restrict__ o) {
  size_t idx = (size_t)blockIdx.x*256 + threadIdx.x;   // over NL*DM*DM
  if (idx >= (size_t)NL*DM*DM) return;
  int r = idx % DM; size_t rest = idx / DM;
  int d = rest % DM; int l = rest / DM;
  o[idx] = __float2bfloat16(wo[(size_t)l*DM*DM + (size_t)r*DM + d]);
}

// plain fp32 -> bf16 cast (batched)
__global__ void k_cast(const float* __restrict__ in, __hip_bfloat16* __restrict__ o, size_t n) {
  size_t idx = (size_t)blockIdx.x*256 + threadIdx.x;
  if (idx < n) o[idx] = __float2bfloat16(in[idx]);
}

// wout (80,768) -> woutb (128,768) bf16, zero-padded rows
__global__ void k_conv_wout(const float* __restrict__ wout, __hip_bfloat16* __restrict__ o) {
  int idx = blockIdx.x*256 + threadIdx.x;     // over 128*DM
  if (idx >= 128*DM) return;
  int n = idx / DM, f = idx % DM;
  o[idx] = __float2bfloat16(n < ODIM ? wout[(size_t)n*DM + f] : 0.f);
}

// ---------------- double-buffered bf16 MFMA GEMM: C[M,N] = A[M,K] * Bt[N,K]^T ----------------
// M-fastest grid (blockIdx.x = m-tile): with Mtiles%8==0, all same-A blocks share an XCD.
// One barrier per K-iter; prefetch of tile i+1 issued after the barrier so the
// global_load_lds stays outstanding across the MFMA block.
template<int BM, int BN, int WM, int WN, bool RELU, bool BF16OUT, bool PERM>
__global__ __launch_bounds__(256)
void k_mfma_gemm(const __hip_bfloat16* __restrict__ A, const __hip_bfloat16* __restrict__ Bt,
                 const float* __restrict__ bias, void* __restrict__ Cv,
                 int K, int Nvalid, int ldc) {
  constexpr int NWN = BN/WN;
  constexpr int FM = WM/16, FN = WN/16;
  __shared__ __align__(16) short As[2][BM*64];
  __shared__ __align__(16) short Bs[2][BN*64];
  const int tid = threadIdx.x;
  const int m0 = blockIdx.x*BM, n0 = blockIdx.y*BN;
  const int lane = tid & 63, w = tid >> 6;
  const int wm = (w / NWN)*WM, wn = (w % NWN)*WN;
  const int mr = lane & 15, q4 = lane >> 4;
  const short* Ag = (const short*)A;
  const short* Bg = (const short*)Bt;
  const v4f zero = {0.f, 0.f, 0.f, 0.f};
  v4f acc[FM][FN];
  #pragma unroll
  for (int i=0;i<FM;++i)
    #pragma unroll
    for (int j=0;j<FN;++j) acc[i][j] = zero;

  auto stage = [&](int k0, int buf) {
    #pragma unroll
    for (int s = 0; s < (BM*8)/256; ++s) {
      int cid = s*256 + tid;
      int row = cid >> 3;
      int c = (cid & 7) ^ (row & 7);
      __builtin_amdgcn_global_load_lds(
        (const __attribute__((address_space(1))) void*)(Ag + (size_t)(m0+row)*K + k0 + c*8),
        (__attribute__((address_space(3))) void*)(&As[buf][cid*8]), 16, 0, 0);
    }
    #pragma unroll
    for (int s = 0; s < (BN*8)/256; ++s) {
      int cid = s*256 + tid;
      int row = cid >> 3;
      int c = (cid & 7) ^ (row & 7);
      __builtin_amdgcn_global_load_lds(
        (const __attribute__((address_space(1))) void*)(Bg + (size_t)(n0+row)*K + k0 + c*8),
        (__attribute__((address_space(3))) void*)(&Bs[buf][cid*8]), 16, 0, 0);
    }
  };

  const int nk = K >> 6;
  stage(0, 0);
  for (int i = 0; i < nk; ++i) {
    __syncthreads();                 // drains tile-i loads; also protects buf reuse
    if (i + 1 < nk) stage((i+1)*64, (i+1)&1);   // outstanding across the MFMAs below
    const short* Ab = As[i&1];
    const short* Bb = Bs[i&1];
    #pragma unroll
    for (int kh = 0; kh < 2; ++kh) {
      int pos = (kh*4 + q4) ^ (mr & 7);
      v8s af[FM], bf[FN];
      #pragma unroll
      for (int ii=0;ii<FM;++ii) af[ii] = *(const v8s*)(Ab + (wm + ii*16 + mr)*64 + pos*8);
      #pragma unroll
      for (int j=0;j<FN;++j) bf[j] = *(const v8s*)(Bb + (wn + j*16 + mr)*64 + pos*8);
      #pragma unroll
      for (int ii=0;ii<FM;++ii)
        #pragma unroll
        for (int j=0;j<FN;++j)
          acc[ii][j] = __builtin_amdgcn_mfma_f32_16x16x32_bf16(af[ii], bf[j], acc[ii][j], 0, 0, 0);
    }
  }

  #pragma unroll
  for (int j=0;j<FN;++j) {
    int col = n0 + wn + j*16 + mr;
    if (col < Nvalid) {
      float bv = bias ? bias[col] : 0.f;
      #pragma unroll
      for (int i=0;i<FM;++i) {
        #pragma unroll
        for (int r=0;r<4;++r) {
          int m = m0 + wm + i*16 + q4*4 + r;
          float val = acc[i][j][r] + bv;
          if (RELU) val = fmaxf(val, 0.f);
          int row = PERM ? ((m & 7)*TT + (m >> 3)) : m;   // token t*8+b -> b*512+t
          if (BF16OUT) ((__hip_bfloat16*)Cv)[(size_t)row*ldc + col] = __float2bfloat16(val);
          else         ((float*)Cv)[(size_t)row*ldc + col] = val;
        }
      }
    }
  }
}

// ---------------- REL precompute: REL[h][n][e] = q_n . emb_h[e], fp32 out ----------------
__global__ __launch_bounds__(256)
void k_rel_gemm(const __hip_bfloat16* __restrict__ qkvb,
                const __hip_bfloat16* __restrict__ embb,
                float* __restrict__ rel) {
  const int e0 = blockIdx.x*64, m0 = blockIdx.y*64, h = blockIdx.z;
  const int tid = threadIdx.x, lane = tid & 63, w = tid >> 6;
  const int l15 = lane & 15, q4 = lane >> 4;
  __shared__ __align__(16) short As[64*104];
  __shared__ __align__(16) short Bs[64*104];
  const short* qg = (const short*)qkvb;
  const short* eg = (const short*)embb;
  {
    int row = tid >> 2;
    const short* sa = qg + (size_t)(m0+row)*NQKV + h*DQ;
    int er = e0 + row; if (er > 200) er = 200;
    const short* sb = eg + ((size_t)h*NREL + er)*DQ;
    short* da = As + row*104;
    short* db = Bs + row*104;
    #pragma unroll
    for (int c = 0; c < 3; ++c) {
      int ch = (tid & 3)*3 + c;
      *(v8s*)(da + ch*8) = *(const v8s*)(sa + ch*8);
      *(v8s*)(db + ch*8) = *(const v8s*)(sb + ch*8);
    }
  }
  __syncthreads();
  const v4f zero = {0.f,0.f,0.f,0.f};
  v4f acc[4] = {zero, zero, zero, zero};
  #pragma unroll
  for (int ks = 0; ks < 3; ++ks) {
    v8s af = *(const v8s*)(As + (w*16 + l15)*104 + ks*32 + q4*8);
    #pragma unroll
    for (int f = 0; f < 4; ++f) {
      v8s bf = *(const v8s*)(Bs + (f*16 + l15)*104 + ks*32 + q4*8);
      acc[f] = __builtin_amdgcn_mfma_f32_16x16x32_bf16(af, bf, acc[f], 0, 0, 0);
    }
  }
  #pragma unroll
  for (int f = 0; f < 4; ++f) {
    int e = e0 + f*16 + l15;
    if (e < 2*WIN + 1) {
      #pragma unroll
      for (int r = 0; r < 4; ++r) {
        int n = m0 + w*16 + q4*4 + r;
        rel[((size_t)h*NTOK + n)*RELD + e] = acc[f][r];
      }
    }
  }
}

// ---------------- banded MFMA attention ----------------
__global__ __launch_bounds__(256)
void k_attn_mfma(const __hip_bfloat16* __restrict__ qkvb,
                 const float* __restrict__ rel,
                 __hip_bfloat16* __restrict__ o) {
  const int qt = blockIdx.x, h = blockIdx.y, b = blockIdx.z;
  const int qlo = qt*64;
  const int tid = threadIdx.x, lane = tid & 63, w = tid >> 6;
  const int l15 = lane & 15, q4 = lane >> 4;
  __shared__ __align__(16) short Qs[64*104];
  __shared__ __align__(16) short Ks[64*104];
  __shared__ __align__(16) short Vt[96*72];
  __shared__ __align__(16) short Ps[64*72];
  const short* qg = (const short*)qkvb;

  {
    int row = tid >> 2;
    const short* src = qg + (size_t)((qlo+row)*8 + b)*NQKV + h*DQ;
    short* dst = Qs + row*104;
    #pragma unroll
    for (int c = 0; c < 3; ++c) {
      int ch = (tid & 3)*3 + c;
      *(v8s*)(dst + ch*8) = *(const v8s*)(src + ch*8);
    }
  }

  v4f sacc[5][4];
  const v4f neg = {-1e30f,-1e30f,-1e30f,-1e30f};
  #pragma unroll
  for (int kt=0;kt<5;++kt)
    #pragma unroll
    for (int f=0;f<4;++f) sacc[kt][f] = neg;

  const int i_row0 = qlo + w*16 + q4*4;   // + r

  // ---- phase 1: S = QK^T + REL ----
  for (int kt = 0; kt < 5; ++kt) {
    int kt0 = qlo + kt*64 - 128;
    if (kt0 + 64 <= 0 || kt0 >= TT) continue;
    {
      int row = tid >> 2;
      int j = kt0 + row; j = j < 0 ? 0 : (j > TT-1 ? TT-1 : j);
      const short* src = qg + (size_t)(j*8 + b)*NQKV + DM + h*DQ;
      short* dst = Ks + row*104;
      #pragma unroll
      for (int c = 0; c < 3; ++c) {
        int ch = (tid & 3)*3 + c;
        *(v8s*)(dst + ch*8) = *(const v8s*)(src + ch*8);
      }
    }
    __syncthreads();
    #pragma unroll
    for (int f = 0; f < 4; ++f) {
      int j = kt0 + f*16 + l15;
      #pragma unroll
      for (int r = 0; r < 4; ++r) {
        int i = i_row0 + r;
        int d = j - i;
        float val = -1e30f;
        if (j >= 0 && j < TT && d >= -WIN && d <= WIN)
          val = rel[((size_t)h*NTOK + i*8 + b)*RELD + d + WIN];
        sacc[kt][f][r] = val;
      }
    }
    #pragma unroll
    for (int ks = 0; ks < 3; ++ks) {
      v8s af = *(const v8s*)(Qs + (w*16 + l15)*104 + ks*32 + q4*8);
      #pragma unroll
      for (int f = 0; f < 4; ++f) {
        v8s bf = *(const v8s*)(Ks + (f*16 + l15)*104 + ks*32 + q4*8);
        sacc[kt][f] = __builtin_amdgcn_mfma_f32_16x16x32_bf16(af, bf, sacc[kt][f], 0, 0, 0);
      }
    }
    __syncthreads();
  }

  // ---- phase 2: softmax in registers ----
  float inv[4];
  #pragma unroll
  for (int r = 0; r < 4; ++r) {
    float m = -1e30f;
    #pragma unroll
    for (int kt=0;kt<5;++kt)
      #pragma unroll
      for (int f=0;f<4;++f) m = fmaxf(m, sacc[kt][f][r]);
    #pragma unroll
    for (int off=1; off<16; off<<=1) m = fmaxf(m, __shfl_xor(m, off));
    float l = 0.f;
    #pragma unroll
    for (int kt=0;kt<5;++kt)
      #pragma unroll
      for (int f=0;f<4;++f) {
        float p = __expf(sacc[kt][f][r] - m);
        sacc[kt][f][r] = p; l += p;
      }
    #pragma unroll
    for (int off=1; off<16; off<<=1) l += __shfl_xor(l, off);
    inv[r] = 1.f / l;
  }

  // ---- phase 3: O = P V ----
  v4f oacc[6];
  const v4f zero = {0.f,0.f,0.f,0.f};
  #pragma unroll
  for (int f=0;f<6;++f) oacc[f] = zero;
  for (int kt = 0; kt < 5; ++kt) {
    int kt0 = qlo + kt*64 - 128;
    if (kt0 + 64 <= 0 || kt0 >= TT) continue;
    #pragma unroll
    for (int f=0;f<4;++f)
      #pragma unroll
      for (int r=0;r<4;++r)
        Ps[(w*16 + q4*4 + r)*72 + f*16 + l15] = bf16bits(sacc[kt][f][r]);
    {
      int j = kt0 + (tid >> 2);
      int jc = j < 0 ? 0 : (j > TT-1 ? TT-1 : j);
      const short* src = qg + (size_t)(jc*8 + b)*NQKV + 2*DM + h*DQ + (tid & 3)*24;
      union { v8s v[3]; short s[24]; } u;
      u.v[0] = *(const v8s*)(src);
      u.v[1] = *(const v8s*)(src + 8);
      u.v[2] = *(const v8s*)(src + 16);
      int a0 = (tid & 3)*24, jl = tid >> 2;
      #pragma unroll
      for (int t=0;t<24;++t) Vt[(a0+t)*72 + jl] = u.s[t];
    }
    __syncthreads();
    #pragma unroll
    for (int ks=0;ks<2;++ks) {
      v8s af = *(const v8s*)(Ps + (w*16 + l15)*72 + ks*32 + q4*8);
      #pragma unroll
      for (int f=0;f<6;++f) {
        v8s bf = *(const v8s*)(Vt + (f*16 + l15)*72 + ks*32 + q4*8);
        oacc[f] = __builtin_amdgcn_mfma_f32_16x16x32_bf16(af, bf, oacc[f], 0, 0, 0);
      }
    }
    __syncthreads();
  }

  #pragma unroll
  for (int f=0;f<6;++f)
    #pragma unroll
    for (int r=0;r<4;++r) {
      int i = i_row0 + r;
      o[(size_t)(i*8 + b)*DM + h*DQ + f*16 + l15] = __float2bfloat16(oacc[f][r] * inv[r]);
    }
}

// ---------------- fused residual + LayerNorm (in-place on src, + bf16 copy) ----------------
__global__ __launch_bounds__(256)
void k_ln_residual(float* __restrict__ src, const float* __restrict__ res,
                   const float* __restrict__ g, const float* __restrict__ bta,
                   __hip_bfloat16* __restrict__ srcb) {
  __shared__ float red[4];
  int n = blockIdx.x;
  float x[3];
  float s = 0.f;
  #pragma unroll
  for (int u=0;u<3;++u) {
    int d = u*256 + threadIdx.x;
    x[u] = src[(size_t)n*DM + d] + res[(size_t)n*DM + d];
    s += x[u];
  }
  #pragma unroll
  for (int off=32; off; off>>=1) s += __shfl_xor(s, off);
  if ((threadIdx.x & 63) == 0) red[threadIdx.x>>6] = s;
  __syncthreads();
  float mu = (red[0]+red[1]+red[2]+red[3]) * (1.f/DM);
  __syncthreads();
  float vs = 0.f;
  #pragma unroll
  for (int u=0;u<3;++u) { float dv = x[u]-mu; vs += dv*dv; }
  #pragma unroll
  for (int off=32; off; off>>=1) vs += __shfl_xor(vs, off);
  if ((threadIdx.x & 63) == 0) red[threadIdx.x>>6] = vs;
  __syncthreads();
  float rstd = rsqrtf((red[0]+red[1]+red[2]+red[3])*(1.f/DM) + 1e-5f);
  #pragma unroll
  for (int u=0;u<3;++u) {
    int d = u*256 + threadIdx.x;
    float v = (x[u]-mu)*rstd*g[d] + bta[d];
    src[(size_t)n*DM + d] = v;
    srcb[(size_t)n*DM + d] = __float2bfloat16(v);
  }
}

extern "C" void kernel_launch(void* const* d_in, const int* in_sizes, int n_in,
                              void* d_out, int out_size, void* d_ws, size_t ws_size,
                              hipStream_t stream) {
  const float* x    = (const float*)d_in[0];
  const float* wq   = (const float*)d_in[1];
  const float* wk   = (const float*)d_in[2];
  const float* wv   = (const float*)d_in[3];
  const float* wo   = (const float*)d_in[4];
  const float* remb = (const float*)d_in[5];
  const float* ff1w = (const float*)d_in[6];
  const float* ff1b = (const float*)d_in[7];
  const float* ff2w = (const float*)d_in[8];
  const float* ff2b = (const float*)d_in[9];
  const float* ln1g = (const float*)d_in[10];
  const float* ln1b = (const float*)d_in[11];
  const float* ln2g = (const float*)d_in[12];
  const float* ln2b = (const float*)d_in[13];
  const float* wout = (const float*)d_in[14];
  const float* bout = (const float*)d_in[15];
  float* out = (float*)d_out;

  float* wsp = (float*)d_ws;
  size_t off = 0;
  float* src  = wsp + off;                              off += (size_t)NTOK*DM;
  __hip_bfloat16* srcb  = (__hip_bfloat16*)(wsp + off); off += (size_t)NTOK*DM/2;
  __hip_bfloat16* qkvb  = (__hip_bfloat16*)(wsp + off); off += (size_t)NTOK*NQKV/2;
  float* rel  = wsp + off;                              off += (size_t)NH*NTOK*RELD;
  float* tmp  = wsp + off;                              off += (size_t)NTOK*DM;
  __hip_bfloat16* qkvwbA = (__hip_bfloat16*)(wsp + off); off += (size_t)NL*NQKV*DM/2;
  __hip_bfloat16* wobA   = (__hip_bfloat16*)(wsp + off); off += (size_t)NL*DM*DM/2;
  __hip_bfloat16* ff1wbA = (__hip_bfloat16*)(wsp + off); off += (size_t)NL*DFF*DM/2;
  __hip_bfloat16* ff2wbA = (__hip_bfloat16*)(wsp + off); off += (size_t)NL*DM*DFF/2;
  __hip_bfloat16* woutb  = (__hip_bfloat16*)(wsp + off); off += (size_t)128*DM/2;
  __hip_bfloat16* embbA  = (__hip_bfloat16*)(wsp + off); off += (size_t)NL*NH*NREL*DQ/2 + 64;
  __hip_bfloat16* hb  = (__hip_bfloat16*)qkvb;  // FF1 out: qkvb(+rel tail) dead post-attention
  __hip_bfloat16* obb = srcb;                   // attention out: srcb dead until LN1 rewrites it
  (void)off; (void)ws_size; (void)in_sizes; (void)n_in; (void)out_size;

  dim3 b256(256);

  // ---- upfront: all weight conversions, batched over layers ----
  k_conv_qkvw<<<dim3(((size_t)NL*NQKV*DM+255)/256), b256, 0, stream>>>(wq, wk, wv, qkvwbA);
  k_conv_wo<<<dim3(((size_t)NL*DM*DM+255)/256), b256, 0, stream>>>(wo, wobA);
  k_cast<<<dim3(((size_t)NL*DFF*DM+255)/256), b256, 0, stream>>>(ff1w, ff1wbA, (size_t)NL*DFF*DM);
  k_cast<<<dim3(((size_t)NL*DM*DFF+255)/256), b256, 0, stream>>>(ff2w, ff2wbA, (size_t)NL*DM*DFF);
  k_cast<<<dim3(((size_t)NL*NH*NREL*DQ+255)/256), b256, 0, stream>>>(remb, embbA, (size_t)NL*NH*NREL*DQ);
  k_conv_wout<<<dim3((128*DM+255)/256), b256, 0, stream>>>(wout, woutb);

  k_transpose_in<<<dim3(NTOK), b256, 0, stream>>>(x, src, srcb);

  for (int l = 0; l < NL; ++l) {
    __hip_bfloat16* qkvwb = qkvwbA + (size_t)l*NQKV*DM;
    __hip_bfloat16* wob   = wobA   + (size_t)l*DM*DM;
    __hip_bfloat16* ff1wb = ff1wbA + (size_t)l*DFF*DM;
    __hip_bfloat16* ff2wb = ff2wbA + (size_t)l*DM*DFF;
    __hip_bfloat16* embb  = embbA  + (size_t)l*NH*NREL*DQ;

    // fused QKV (bf16 out): (4096 x 2304), M-fastest grid
    k_mfma_gemm<64,128,64,32,false,true,false><<<dim3(NTOK/64, NQKV/128), b256, 0, stream>>>(
        srcb, qkvwb, nullptr, qkvb, DM, NQKV, NQKV);

    // REL[h][n][e] = q . emb
    k_rel_gemm<<<dim3(4, NTOK/64, NH), b256, 0, stream>>>(qkvb, embb, rel);

    // banded MFMA attention
    k_attn_mfma<<<dim3(TT/64, NH, BB), b256, 0, stream>>>(qkvb, rel, obb);

    // O-proj: tmp = obb * wob^T   (64x64 tiles, 768 blocks)
    k_mfma_gemm<64,64,32,32,false,false,false><<<dim3(NTOK/64, DM/64), b256, 0, stream>>>(
        obb, wob, nullptr, tmp, DM, DM, DM);
    k_ln_residual<<<dim3(NTOK), b256, 0, stream>>>(src, tmp, ln1g + (size_t)l*DM, ln1b + (size_t)l*DM, srcb);

    // FF1: hb = relu(srcb * ff1wb^T + b), bf16 out
    k_mfma_gemm<64,128,64,32,true,true,false><<<dim3(NTOK/64, DFF/128), b256, 0, stream>>>(
        srcb, ff1wb, ff1b + (size_t)l*DFF, hb, DM, DFF, DFF);
    // FF2: tmp = hb * ff2wb^T + b   (64x64 tiles, 768 blocks)
    k_mfma_gemm<64,64,32,32,false,false,false><<<dim3(NTOK/64, DM/64), b256, 0, stream>>>(
        hb, ff2wb, ff2b + (size_t)l*DM, tmp, DFF, DM, DM);
    k_ln_residual<<<dim3(NTOK), b256, 0, stream>>>(src, tmp, ln2g + (size_t)l*DM, ln2b + (size_t)l*DM, srcb);
  }

  k_mfma_gemm<64,128,64,32,false,false,true><<<dim3(NTOK/64, 1), b256, 0, stream>>>(
      srcb, woutb, bout, out, DM, ODIM, ODIM);
}

// Round 5
// 1146.936 us; speedup vs baseline: 7.1747x; 1.1381x over previous
//
#include <hip/hip_runtime.h>
#include <hip/hip_bf16.h>
#include <math.h>

#define NL   6
#define DM   768
#define NH   8
#define DQ   96
#define DFF  3072
#define BB   8
#define TT   512
#define NTOK (BB*TT)      // 4096 tokens
#define NREL 201
#define WIN  99
#define ODIM 80
#define NQKV 2304         // fused q|k|v columns
#define RELD 208          // padded e-dim of REL buffer

typedef __attribute__((ext_vector_type(8))) short v8s;
typedef __attribute__((ext_vector_type(4))) float v4f;

static __device__ __forceinline__ short bf16bits(float x) {
  __hip_bfloat16 h = __float2bfloat16(x);
  return *(short*)&h;
}
static __device__ __forceinline__ unsigned short bf16u(float x) {
  __hip_bfloat16 h = __float2bfloat16(x);
  return *(unsigned short*)&h;
}

// ---------------- input transpose: x(B,T,D) -> src(token n=t*8+b, D) fp32 + bf16 ----------------
__global__ void k_transpose_in(const float* __restrict__ x, float* __restrict__ src,
                               __hip_bfloat16* __restrict__ srcb) {
  int n = blockIdx.x;               // n = t*8 + b
  int t = n >> 3, b = n & 7;
  const float* xi = x + ((size_t)b*TT + t)*DM;
  for (int d = threadIdx.x; d < DM; d += blockDim.x) {
    float v = xi[d];
    src[(size_t)n*DM + d] = v;
    srcb[(size_t)n*DM + d] = __float2bfloat16(v);
  }
}

// ---------------- LDS-tiled weight transposes (coalesced both sides) ----------------
// wq/wk/wv[l][h][f][a] -> qkvwb[l][part*768 + h*96+a][f]; qscale folded into q part.
// grid: (ftile 12, atile 3, l*8+h); 64(f) x 32(a) fp32 tiles.
__global__ __launch_bounds__(256)
void k_conv_qkvw(const float* __restrict__ wq, const float* __restrict__ wk,
                 const float* __restrict__ wv, __hip_bfloat16* __restrict__ o) {
  __shared__ float tile[64][33];
  const int ft = blockIdx.x, at = blockIdx.y;
  const int l = blockIdx.z >> 3, h = blockIdx.z & 7;
  const int f0 = ft*64, a0 = at*32;
  const int tx = threadIdx.x & 31, ty = threadIdx.x >> 5;
  const float* srcs[3] = {wq, wk, wv};
  #pragma unroll
  for (int part = 0; part < 3; ++part) {
    const float* s = srcs[part] + (size_t)l*DM*DM + (size_t)h*DM*DQ;   // [f][a]
    #pragma unroll
    for (int p = 0; p < 8; ++p)
      tile[ty + 8*p][tx] = s[(size_t)(f0 + ty + 8*p)*DQ + (a0 + tx)];
    __syncthreads();
    const float sc = (part == 0) ? 0.10206207261596577f : 1.f;
    unsigned short* d = (unsigned short*)o + (size_t)l*NQKV*DM + (size_t)(part*DM + h*DQ)*DM;
    #pragma unroll
    for (int p = 0; p < 4; ++p) {
      int a = ty + 8*p;
      int f = 2*tx;
      ushort2 pr = make_ushort2(bf16u(tile[f][a]*sc), bf16u(tile[f+1][a]*sc));
      *(ushort2*)(d + (size_t)(a0 + a)*DM + f0 + f) = pr;
    }
    __syncthreads();
  }
}

// wo[l][r][d] -> wob[l][d][r]; grid (rtile 12, dtile 24, l); 64(r) x 32(d) tiles.
__global__ __launch_bounds__(256)
void k_conv_wo(const float* __restrict__ wo, __hip_bfloat16* __restrict__ o) {
  __shared__ float tile[64][33];
  const int rt = blockIdx.x, dt = blockIdx.y, l = blockIdx.z;
  const int r0 = rt*64, d0 = dt*32;
  const int tx = threadIdx.x & 31, ty = threadIdx.x >> 5;
  const float* s = wo + (size_t)l*DM*DM;
  #pragma unroll
  for (int p = 0; p < 8; ++p)
    tile[ty + 8*p][tx] = s[(size_t)(r0 + ty + 8*p)*DM + d0 + tx];
  __syncthreads();
  unsigned short* d = (unsigned short*)o + (size_t)l*DM*DM;
  #pragma unroll
  for (int p = 0; p < 4; ++p) {
    int dd = ty + 8*p;
    int r = 2*tx;
    ushort2 pr = make_ushort2(bf16u(tile[r][dd]), bf16u(tile[r+1][dd]));
    *(ushort2*)(d + (size_t)(d0 + dd)*DM + r0 + r) = pr;
  }
}

// plain fp32 -> bf16 cast (batched, coalesced)
__global__ void k_cast(const float* __restrict__ in, __hip_bfloat16* __restrict__ o, size_t n) {
  size_t idx = (size_t)blockIdx.x*256 + threadIdx.x;
  if (idx < n) o[idx] = __float2bfloat16(in[idx]);
}

// wout (80,768) -> woutb (128,768) bf16, zero-padded rows
__global__ void k_conv_wout(const float* __restrict__ wout, __hip_bfloat16* __restrict__ o) {
  int idx = blockIdx.x*256 + threadIdx.x;     // over 128*DM
  if (idx >= 128*DM) return;
  int n = idx / DM, f = idx % DM;
  o[idx] = __float2bfloat16(n < ODIM ? wout[(size_t)n*DM + f] : 0.f);
}

// ---------------- bf16 MFMA GEMM: C[M,N] = A[M,K] * Bt[N,K]^T ----------------
// M-fastest grid (blockIdx.x = m-tile); DBUF selects explicit double-buffered K-loop.
template<int BM, int BN, int WM, int WN, bool DBUF, bool RELU, bool BF16OUT, bool PERM>
__global__ __launch_bounds__(256)
void k_mfma_gemm(const __hip_bfloat16* __restrict__ A, const __hip_bfloat16* __restrict__ Bt,
                 const float* __restrict__ bias, void* __restrict__ Cv,
                 int K, int Nvalid, int ldc) {
  constexpr int NWN = BN/WN;
  constexpr int FM = WM/16, FN = WN/16;
  constexpr int NB = DBUF ? 2 : 1;
  __shared__ __align__(16) short As[NB][BM*64];
  __shared__ __align__(16) short Bs[NB][BN*64];
  const int tid = threadIdx.x;
  const int m0 = blockIdx.x*BM, n0 = blockIdx.y*BN;
  const int lane = tid & 63, w = tid >> 6;
  const int wm = (w / NWN)*WM, wn = (w % NWN)*WN;
  const int mr = lane & 15, q4 = lane >> 4;
  const short* Ag = (const short*)A;
  const short* Bg = (const short*)Bt;
  const v4f zero = {0.f, 0.f, 0.f, 0.f};
  v4f acc[FM][FN];
  #pragma unroll
  for (int i=0;i<FM;++i)
    #pragma unroll
    for (int j=0;j<FN;++j) acc[i][j] = zero;

  auto stage = [&](int k0, int buf) {
    #pragma unroll
    for (int s = 0; s < (BM*8)/256; ++s) {
      int cid = s*256 + tid;
      int row = cid >> 3;
      int c = (cid & 7) ^ (row & 7);
      __builtin_amdgcn_global_load_lds(
        (const __attribute__((address_space(1))) void*)(Ag + (size_t)(m0+row)*K + k0 + c*8),
        (__attribute__((address_space(3))) void*)(&As[buf][cid*8]), 16, 0, 0);
    }
    #pragma unroll
    for (int s = 0; s < (BN*8)/256; ++s) {
      int cid = s*256 + tid;
      int row = cid >> 3;
      int c = (cid & 7) ^ (row & 7);
      __builtin_amdgcn_global_load_lds(
        (const __attribute__((address_space(1))) void*)(Bg + (size_t)(n0+row)*K + k0 + c*8),
        (__attribute__((address_space(3))) void*)(&Bs[buf][cid*8]), 16, 0, 0);
    }
  };

  auto compute = [&](const short* Ab, const short* Bb) {
    #pragma unroll
    for (int kh = 0; kh < 2; ++kh) {
      int pos = (kh*4 + q4) ^ (mr & 7);
      v8s af[FM], bf[FN];
      #pragma unroll
      for (int ii=0;ii<FM;++ii) af[ii] = *(const v8s*)(Ab + (wm + ii*16 + mr)*64 + pos*8);
      #pragma unroll
      for (int j=0;j<FN;++j) bf[j] = *(const v8s*)(Bb + (wn + j*16 + mr)*64 + pos*8);
      #pragma unroll
      for (int ii=0;ii<FM;++ii)
        #pragma unroll
        for (int j=0;j<FN;++j)
          acc[ii][j] = __builtin_amdgcn_mfma_f32_16x16x32_bf16(af[ii], bf[j], acc[ii][j], 0, 0, 0);
    }
  };

  const int nk = K >> 6;
  if (DBUF) {
    stage(0, 0);
    for (int i = 0; i < nk; ++i) {
      __syncthreads();
      if (i + 1 < nk) stage((i+1)*64, (i+1)&1);
      compute(As[i&1], Bs[i&1]);
    }
  } else {
    for (int i = 0; i < nk; ++i) {
      stage(i*64, 0);
      __syncthreads();
      compute(As[0], Bs[0]);
      __syncthreads();
    }
  }

  #pragma unroll
  for (int j=0;j<FN;++j) {
    int col = n0 + wn + j*16 + mr;
    if (col < Nvalid) {
      float bv = bias ? bias[col] : 0.f;
      #pragma unroll
      for (int i=0;i<FM;++i) {
        #pragma unroll
        for (int r=0;r<4;++r) {
          int m = m0 + wm + i*16 + q4*4 + r;
          float val = acc[i][j][r] + bv;
          if (RELU) val = fmaxf(val, 0.f);
          int row = PERM ? ((m & 7)*TT + (m >> 3)) : m;   // token t*8+b -> b*512+t
          if (BF16OUT) ((__hip_bfloat16*)Cv)[(size_t)row*ldc + col] = __float2bfloat16(val);
          else         ((float*)Cv)[(size_t)row*ldc + col] = val;
        }
      }
    }
  }
}

// ---------------- REL precompute: REL[h][n][e] = q_n . emb_h[e], fp32 out ----------------
__global__ __launch_bounds__(256)
void k_rel_gemm(const __hip_bfloat16* __restrict__ qkvb,
                const __hip_bfloat16* __restrict__ embb,
                float* __restrict__ rel) {
  const int e0 = blockIdx.x*64, m0 = blockIdx.y*64, h = blockIdx.z;
  const int tid = threadIdx.x, lane = tid & 63, w = tid >> 6;
  const int l15 = lane & 15, q4 = lane >> 4;
  __shared__ __align__(16) short As[64*104];
  __shared__ __align__(16) short Bs[64*104];
  const short* qg = (const short*)qkvb;
  const short* eg = (const short*)embb;
  {
    int row = tid >> 2;
    const short* sa = qg + (size_t)(m0+row)*NQKV + h*DQ;
    int er = e0 + row; if (er > 200) er = 200;
    const short* sb = eg + ((size_t)h*NREL + er)*DQ;
    short* da = As + row*104;
    short* db = Bs + row*104;
    #pragma unroll
    for (int c = 0; c < 3; ++c) {
      int ch = (tid & 3)*3 + c;
      *(v8s*)(da + ch*8) = *(const v8s*)(sa + ch*8);
      *(v8s*)(db + ch*8) = *(const v8s*)(sb + ch*8);
    }
  }
  __syncthreads();
  const v4f zero = {0.f,0.f,0.f,0.f};
  v4f acc[4] = {zero, zero, zero, zero};
  #pragma unroll
  for (int ks = 0; ks < 3; ++ks) {
    v8s af = *(const v8s*)(As + (w*16 + l15)*104 + ks*32 + q4*8);
    #pragma unroll
    for (int f = 0; f < 4; ++f) {
      v8s bf = *(const v8s*)(Bs + (f*16 + l15)*104 + ks*32 + q4*8);
      acc[f] = __builtin_amdgcn_mfma_f32_16x16x32_bf16(af, bf, acc[f], 0, 0, 0);
    }
  }
  #pragma unroll
  for (int f = 0; f < 4; ++f) {
    int e = e0 + f*16 + l15;
    if (e < 2*WIN + 1) {
      #pragma unroll
      for (int r = 0; r < 4; ++r) {
        int n = m0 + w*16 + q4*4 + r;
        rel[((size_t)h*NTOK + n)*RELD + e] = acc[f][r];
      }
    }
  }
}

// ---------------- banded MFMA attention ----------------
__global__ __launch_bounds__(256)
void k_attn_mfma(const __hip_bfloat16* __restrict__ qkvb,
                 const float* __restrict__ rel,
                 __hip_bfloat16* __restrict__ o) {
  const int qt = blockIdx.x, h = blockIdx.y, b = blockIdx.z;
  const int qlo = qt*64;
  const int tid = threadIdx.x, lane = tid & 63, w = tid >> 6;
  const int l15 = lane & 15, q4 = lane >> 4;
  __shared__ __align__(16) short Qs[64*104];
  __shared__ __align__(16) short Ks[64*104];
  __shared__ __align__(16) short Vt[96*72];
  __shared__ __align__(16) short Ps[64*72];
  const short* qg = (const short*)qkvb;

  {
    int row = tid >> 2;
    const short* src = qg + (size_t)((qlo+row)*8 + b)*NQKV + h*DQ;
    short* dst = Qs + row*104;
    #pragma unroll
    for (int c = 0; c < 3; ++c) {
      int ch = (tid & 3)*3 + c;
      *(v8s*)(dst + ch*8) = *(const v8s*)(src + ch*8);
    }
  }

  v4f sacc[5][4];
  const v4f neg = {-1e30f,-1e30f,-1e30f,-1e30f};
  #pragma unroll
  for (int kt=0;kt<5;++kt)
    #pragma unroll
    for (int f=0;f<4;++f) sacc[kt][f] = neg;

  const int i_row0 = qlo + w*16 + q4*4;   // + r

  // ---- phase 1: S = QK^T + REL ----
  for (int kt = 0; kt < 5; ++kt) {
    int kt0 = qlo + kt*64 - 128;
    if (kt0 + 64 <= 0 || kt0 >= TT) continue;
    {
      int row = tid >> 2;
      int j = kt0 + row; j = j < 0 ? 0 : (j > TT-1 ? TT-1 : j);
      const short* src = qg + (size_t)(j*8 + b)*NQKV + DM + h*DQ;
      short* dst = Ks + row*104;
      #pragma unroll
      for (int c = 0; c < 3; ++c) {
        int ch = (tid & 3)*3 + c;
        *(v8s*)(dst + ch*8) = *(const v8s*)(src + ch*8);
      }
    }
    __syncthreads();
    #pragma unroll
    for (int f = 0; f < 4; ++f) {
      int j = kt0 + f*16 + l15;
      #pragma unroll
      for (int r = 0; r < 4; ++r) {
        int i = i_row0 + r;
        int d = j - i;
        float val = -1e30f;
        if (j >= 0 && j < TT && d >= -WIN && d <= WIN)
          val = rel[((size_t)h*NTOK + i*8 + b)*RELD + d + WIN];
        sacc[kt][f][r] = val;
      }
    }
    #pragma unroll
    for (int ks = 0; ks < 3; ++ks) {
      v8s af = *(const v8s*)(Qs + (w*16 + l15)*104 + ks*32 + q4*8);
      #pragma unroll
      for (int f = 0; f < 4; ++f) {
        v8s bf = *(const v8s*)(Ks + (f*16 + l15)*104 + ks*32 + q4*8);
        sacc[kt][f] = __builtin_amdgcn_mfma_f32_16x16x32_bf16(af, bf, sacc[kt][f], 0, 0, 0);
      }
    }
    __syncthreads();
  }

  // ---- phase 2: softmax in registers ----
  float inv[4];
  #pragma unroll
  for (int r = 0; r < 4; ++r) {
    float m = -1e30f;
    #pragma unroll
    for (int kt=0;kt<5;++kt)
      #pragma unroll
      for (int f=0;f<4;++f) m = fmaxf(m, sacc[kt][f][r]);
    #pragma unroll
    for (int off=1; off<16; off<<=1) m = fmaxf(m, __shfl_xor(m, off));
    float l = 0.f;
    #pragma unroll
    for (int kt=0;kt<5;++kt)
      #pragma unroll
      for (int f=0;f<4;++f) {
        float p = __expf(sacc[kt][f][r] - m);
        sacc[kt][f][r] = p; l += p;
      }
    #pragma unroll
    for (int off=1; off<16; off<<=1) l += __shfl_xor(l, off);
    inv[r] = 1.f / l;
  }

  // ---- phase 3: O = P V ----
  v4f oacc[6];
  const v4f zero = {0.f,0.f,0.f,0.f};
  #pragma unroll
  for (int f=0;f<6;++f) oacc[f] = zero;
  for (int kt = 0; kt < 5; ++kt) {
    int kt0 = qlo + kt*64 - 128;
    if (kt0 + 64 <= 0 || kt0 >= TT) continue;
    #pragma unroll
    for (int f=0;f<4;++f)
      #pragma unroll
      for (int r=0;r<4;++r)
        Ps[(w*16 + q4*4 + r)*72 + f*16 + l15] = bf16bits(sacc[kt][f][r]);
    {
      int j = kt0 + (tid >> 2);
      int jc = j < 0 ? 0 : (j > TT-1 ? TT-1 : j);
      const short* src = qg + (size_t)(jc*8 + b)*NQKV + 2*DM + h*DQ + (tid & 3)*24;
      union { v8s v[3]; short s[24]; } u;
      u.v[0] = *(const v8s*)(src);
      u.v[1] = *(const v8s*)(src + 8);
      u.v[2] = *(const v8s*)(src + 16);
      int a0 = (tid & 3)*24, jl = tid >> 2;
      #pragma unroll
      for (int t=0;t<24;++t) Vt[(a0+t)*72 + jl] = u.s[t];
    }
    __syncthreads();
    #pragma unroll
    for (int ks=0;ks<2;++ks) {
      v8s af = *(const v8s*)(Ps + (w*16 + l15)*72 + ks*32 + q4*8);
      #pragma unroll
      for (int f=0;f<6;++f) {
        v8s bf = *(const v8s*)(Vt + (f*16 + l15)*72 + ks*32 + q4*8);
        oacc[f] = __builtin_amdgcn_mfma_f32_16x16x32_bf16(af, bf, oacc[f], 0, 0, 0);
      }
    }
    __syncthreads();
  }

  #pragma unroll
  for (int f=0;f<6;++f)
    #pragma unroll
    for (int r=0;r<4;++r) {
      int i = i_row0 + r;
      o[(size_t)(i*8 + b)*DM + h*DQ + f*16 + l15] = __float2bfloat16(oacc[f][r] * inv[r]);
    }
}

// ---------------- fused residual + LayerNorm (in-place on src, + bf16 copy) ----------------
__global__ __launch_bounds__(256)
void k_ln_residual(float* __restrict__ src, const float* __restrict__ res,
                   const float* __restrict__ g, const float* __restrict__ bta,
                   __hip_bfloat16* __restrict__ srcb) {
  __shared__ float red[4];
  int n = blockIdx.x;
  float x[3];
  float s = 0.f;
  #pragma unroll
  for (int u=0;u<3;++u) {
    int d = u*256 + threadIdx.x;
    x[u] = src[(size_t)n*DM + d] + res[(size_t)n*DM + d];
    s += x[u];
  }
  #pragma unroll
  for (int off=32; off; off>>=1) s += __shfl_xor(s, off);
  if ((threadIdx.x & 63) == 0) red[threadIdx.x>>6] = s;
  __syncthreads();
  float mu = (red[0]+red[1]+red[2]+red[3]) * (1.f/DM);
  __syncthreads();
  float vs = 0.f;
  #pragma unroll
  for (int u=0;u<3;++u) { float dv = x[u]-mu; vs += dv*dv; }
  #pragma unroll
  for (int off=32; off; off>>=1) vs += __shfl_xor(vs, off);
  if ((threadIdx.x & 63) == 0) red[threadIdx.x>>6] = vs;
  __syncthreads();
  float rstd = rsqrtf((red[0]+red[1]+red[2]+red[3])*(1.f/DM) + 1e-5f);
  #pragma unroll
  for (int u=0;u<3;++u) {
    int d = u*256 + threadIdx.x;
    float v = (x[u]-mu)*rstd*g[d] + bta[d];
    src[(size_t)n*DM + d] = v;
    srcb[(size_t)n*DM + d] = __float2bfloat16(v);
  }
}

extern "C" void kernel_launch(void* const* d_in, const int* in_sizes, int n_in,
                              void* d_out, int out_size, void* d_ws, size_t ws_size,
                              hipStream_t stream) {
  const float* x    = (const float*)d_in[0];
  const float* wq   = (const float*)d_in[1];
  const float* wk   = (const float*)d_in[2];
  const float* wv   = (const float*)d_in[3];
  const float* wo   = (const float*)d_in[4];
  const float* remb = (const float*)d_in[5];
  const float* ff1w = (const float*)d_in[6];
  const float* ff1b = (const float*)d_in[7];
  const float* ff2w = (const float*)d_in[8];
  const float* ff2b = (const float*)d_in[9];
  const float* ln1g = (const float*)d_in[10];
  const float* ln1b = (const float*)d_in[11];
  const float* ln2g = (const float*)d_in[12];
  const float* ln2b = (const float*)d_in[13];
  const float* wout = (const float*)d_in[14];
  const float* bout = (const float*)d_in[15];
  float* out = (float*)d_out;

  float* wsp = (float*)d_ws;
  size_t off = 0;
  float* src  = wsp + off;                              off += (size_t)NTOK*DM;
  __hip_bfloat16* srcb  = (__hip_bfloat16*)(wsp + off); off += (size_t)NTOK*DM/2;
  __hip_bfloat16* qkvb  = (__hip_bfloat16*)(wsp + off); off += (size_t)NTOK*NQKV/2;
  float* rel  = wsp + off;                              off += (size_t)NH*NTOK*RELD;
  float* tmp  = wsp + off;                              off += (size_t)NTOK*DM;
  __hip_bfloat16* qkvwbA = (__hip_bfloat16*)(wsp + off); off += (size_t)NL*NQKV*DM/2;
  __hip_bfloat16* wobA   = (__hip_bfloat16*)(wsp + off); off += (size_t)NL*DM*DM/2;
  __hip_bfloat16* ff1wbA = (__hip_bfloat16*)(wsp + off); off += (size_t)NL*DFF*DM/2;
  __hip_bfloat16* ff2wbA = (__hip_bfloat16*)(wsp + off); off += (size_t)NL*DM*DFF/2;
  __hip_bfloat16* woutb  = (__hip_bfloat16*)(wsp + off); off += (size_t)128*DM/2;
  __hip_bfloat16* embbA  = (__hip_bfloat16*)(wsp + off); off += (size_t)NL*NH*NREL*DQ/2 + 64;
  __hip_bfloat16* hb  = (__hip_bfloat16*)qkvb;  // FF1 out: qkvb(+rel tail) dead post-attention
  __hip_bfloat16* obb = srcb;                   // attention out: srcb dead until LN1 rewrites it
  (void)off; (void)ws_size; (void)in_sizes; (void)n_in; (void)out_size;

  dim3 b256(256);

  // ---- upfront: all weight conversions, batched over layers ----
  k_conv_qkvw<<<dim3(DM/64, DQ/32, NL*NH), b256, 0, stream>>>(wq, wk, wv, qkvwbA);
  k_conv_wo<<<dim3(DM/64, DM/32, NL), b256, 0, stream>>>(wo, wobA);
  k_cast<<<dim3(((size_t)NL*DFF*DM+255)/256), b256, 0, stream>>>(ff1w, ff1wbA, (size_t)NL*DFF*DM);
  k_cast<<<dim3(((size_t)NL*DM*DFF+255)/256), b256, 0, stream>>>(ff2w, ff2wbA, (size_t)NL*DM*DFF);
  k_cast<<<dim3(((size_t)NL*NH*NREL*DQ+255)/256), b256, 0, stream>>>(remb, embbA, (size_t)NL*NH*NREL*DQ);
  k_conv_wout<<<dim3((128*DM+255)/256), b256, 0, stream>>>(wout, woutb);

  k_transpose_in<<<dim3(NTOK), b256, 0, stream>>>(x, src, srcb);

  for (int l = 0; l < NL; ++l) {
    __hip_bfloat16* qkvwb = qkvwbA + (size_t)l*NQKV*DM;
    __hip_bfloat16* wob   = wobA   + (size_t)l*DM*DM;
    __hip_bfloat16* ff1wb = ff1wbA + (size_t)l*DFF*DM;
    __hip_bfloat16* ff2wb = ff2wbA + (size_t)l*DM*DFF;
    __hip_bfloat16* embb  = embbA  + (size_t)l*NH*NREL*DQ;

    // fused QKV (bf16 out): (4096 x 2304), m97-shape 128x128 single-buffer
    k_mfma_gemm<128,128,64,64,false,false,true,false><<<dim3(NTOK/128, NQKV/128), b256, 0, stream>>>(
        srcb, qkvwb, nullptr, qkvb, DM, NQKV, NQKV);

    // REL[h][n][e] = q . emb
    k_rel_gemm<<<dim3(4, NTOK/64, NH), b256, 0, stream>>>(qkvb, embb, rel);

    // banded MFMA attention
    k_attn_mfma<<<dim3(TT/64, NH, BB), b256, 0, stream>>>(qkvb, rel, obb);

    // O-proj: tmp = obb * wob^T   (64x64 dbuf tiles, 768 blocks)
    k_mfma_gemm<64,64,32,32,true,false,false,false><<<dim3(NTOK/64, DM/64), b256, 0, stream>>>(
        obb, wob, nullptr, tmp, DM, DM, DM);
    k_ln_residual<<<dim3(NTOK), b256, 0, stream>>>(src, tmp, ln1g + (size_t)l*DM, ln1b + (size_t)l*DM, srcb);

    // FF1: hb = relu(srcb * ff1wb^T + b), bf16 out, 128x128 single-buffer
    k_mfma_gemm<128,128,64,64,false,true,true,false><<<dim3(NTOK/128, DFF/128), b256, 0, stream>>>(
        srcb, ff1wb, ff1b + (size_t)l*DFF, hb, DM, DFF, DFF);
    // FF2: tmp = hb * ff2wb^T + b   (64x64 dbuf tiles, 768 blocks)
    k_mfma_gemm<64,64,32,32,true,false,false,false><<<dim3(NTOK/64, DM/64), b256, 0, stream>>>(
        hb, ff2wb, ff2b + (size_t)l*DM, tmp, DFF, DM, DM);
    k_ln_residual<<<dim3(NTOK), b256, 0, stream>>>(src, tmp, ln2g + (size_t)l*DM, ln2b + (size_t)l*DM, srcb);
  }

  k_mfma_gemm<64,128,64,32,true,false,false,true><<<dim3(NTOK/64, 1), b256, 0, stream>>>(
      srcb, woutb, bout, out, DM, ODIM, ODIM);
}